// Round 9
// baseline (3597.199 us; speedup 1.0000x reference)
//
#include <hip/hip_runtime.h>
#include <math.h>

#define HD 128
#define LDP 136   // padded LDS row stride in f16 elems
#define CSH 12    // coarse bucket shift (4096 dst per bucket)
#define CMSK 4095
#define NSUB 32   // contention-splitting sub-counters per coarse bucket

typedef _Float16 f16;
typedef _Float16 f16x8 __attribute__((ext_vector_type(8)));
typedef float f32x4 __attribute__((ext_vector_type(4)));
typedef unsigned int u32x4 __attribute__((ext_vector_type(4)));

static __device__ __forceinline__ float h2f(unsigned short s) {
    f16 v; __builtin_memcpy(&v, &s, 2); return (float)v;
}

// ---------------------------------------------------------------- diagnostic
__global__ void k_diag(float* __restrict__ out, int n, float val) {
    for (int i = blockIdx.x * blockDim.x + threadIdx.x; i < n; i += gridDim.x * blockDim.x)
        out[i] = val;
}

// ---------------------------------------------------------------- utility
__global__ void k_zero(float* __restrict__ p, int n) {
    for (int i = threadIdx.x; i < n; i += blockDim.x) p[i] = 0.f;
}
__global__ void k_zeroi(int* __restrict__ p, int n) {
    for (int i = blockIdx.x * blockDim.x + threadIdx.x; i < n; i += gridDim.x * blockDim.x)
        p[i] = 0;
}
__global__ void k_copyi(const int* __restrict__ a, int* __restrict__ b, int n) {
    for (int i = blockIdx.x * blockDim.x + threadIdx.x; i < n; i += gridDim.x * blockDim.x)
        b[i] = a[i];
}

// ---------------------------------------------------------------- CSR build
// fine counts (row_ptr[d+1]) and coarse sub-counter counts in one dst pass
__global__ void k_hist2(const int* __restrict__ dst, int* __restrict__ row_ptr,
                        int* __restrict__ ccnt, int e) {
    const int s = blockIdx.x & (NSUB - 1);
    for (int i = blockIdx.x * blockDim.x + threadIdx.x; i < e; i += gridDim.x * blockDim.x) {
        int d = dst[i];
        atomicAdd(&row_ptr[d + 1], 1);
        atomicAdd(&ccnt[((d >> CSH) * NSUB + s) + 1], 1);
    }
}

#define SCAN_B 1024
__global__ void k_scan_block(int* __restrict__ a, int n, int* __restrict__ bsum) {
    __shared__ int s[SCAN_B];
    int base = blockIdx.x * SCAN_B;
    int i = base + threadIdx.x;
    int v = (i < n) ? a[i] : 0;
    s[threadIdx.x] = v;
    __syncthreads();
    for (int o = 1; o < SCAN_B; o <<= 1) {
        int t = (threadIdx.x >= o) ? s[threadIdx.x - o] : 0;
        __syncthreads();
        s[threadIdx.x] += t;
        __syncthreads();
    }
    if (i < n) a[i] = s[threadIdx.x];
    if (threadIdx.x == 0) bsum[blockIdx.x] = s[SCAN_B - 1];
}
__global__ void k_scan_serial(int* __restrict__ bsum, int nb) {
    int run = 0;
    for (int b = 0; b < nb; b++) { int t = bsum[b]; bsum[b] = run; run += t; }
}
__global__ void k_scan_add(int* __restrict__ a, int n, const int* __restrict__ bsum) {
    int base = blockIdx.x * SCAN_B;
    int i = base + threadIdx.x;
    if (i < n) a[i] += bsum[blockIdx.x];
}

// pass 1: partition edges into coarse buckets; per-(bucket,sub) write streams
// are sequential -> no write amplification. entry = (src<<12) | (dst&4095)
__global__ void k_partition(const int* __restrict__ src, const int* __restrict__ dst,
                            int* __restrict__ cfill, int* __restrict__ tmp, int e) {
    const int s = blockIdx.x & (NSUB - 1);
    for (int i = blockIdx.x * blockDim.x + threadIdx.x; i < e; i += gridDim.x * blockDim.x) {
        int d = dst[i];
        int pos = atomicAdd(&cfill[(d >> CSH) * NSUB + s], 1);
        tmp[pos] = (src[i] << CSH) | (d & CMSK);
    }
}

// pass 2: fine scatter within one coarse bucket (write region ~262KB, L2-local)
__global__ void k_bucket2(const int* __restrict__ tmp, const int* __restrict__ coff,
                          int* __restrict__ fill, int* __restrict__ src_sorted) {
    const int b = blockIdx.x >> 2, q = blockIdx.x & 3;
    const int lo = coff[b * NSUB], hi = coff[(b + 1) * NSUB];
    for (int i = lo + q * blockDim.x + threadIdx.x; i < hi; i += 4 * blockDim.x) {
        int e2 = tmp[i];
        int d = (b << CSH) | (e2 & CMSK);
        int pos = atomicAdd(&fill[d], 1);
        src_sorted[pos] = ((unsigned int)e2) >> CSH;
    }
}

// ---------------------------------------------------------------- layer 0
__global__ void k_pool0(const float* __restrict__ vf, const int* __restrict__ row_ptr,
                        const int* __restrict__ srcs, const float* __restrict__ eps,
                        float* __restrict__ p0, int n) {
    float ep = 1.f + eps[0];
    for (int i = blockIdx.x * blockDim.x + threadIdx.x; i < n; i += gridDim.x * blockDim.x) {
        float s = ep * vf[i];
        int j1 = row_ptr[i + 1];
        for (int j = row_ptr[i]; j < j1; j++) s += vf[srcs[j]];
        p0[i] = s;
    }
}

__global__ void k_p0_stats(const float* __restrict__ p0, float* __restrict__ stats, int n) {
    __shared__ float rs[256], rq[256];
    float s = 0.f, q = 0.f;
    for (int i = blockIdx.x * blockDim.x + threadIdx.x; i < n; i += gridDim.x * blockDim.x) {
        float v = p0[i]; s += v; q += v * v;
    }
    int t = threadIdx.x;
    rs[t] = s; rq[t] = q;
    __syncthreads();
    for (int o = 128; o > 0; o >>= 1) {
        if (t < o) { rs[t] += rs[t + o]; rq[t] += rq[t + o]; }
        __syncthreads();
    }
    if (t == 0) { unsafeAtomicAdd(&stats[0], rs[0]); unsafeAtomicAdd(&stats[1], rq[0]); }
}

__global__ void k_l0_prep(float* __restrict__ stats, const float* __restrict__ W1,
                          const float* __restrict__ g1, const float* __restrict__ bb1,
                          float* __restrict__ A0, float* __restrict__ Sh0, int n) {
    float mp = stats[0] / n;
    float vp = stats[1] / n - mp * mp;
    int c = threadIdx.x;
    float w = W1[c];
    A0[c] = w * rsqrtf(vp * w * w + 1e-5f) * g1[c];
    Sh0[c] = bb1[c];
    if (c == 0) stats[2] = mp;
}

// ---------------------------------------------------------------- BN+ReLU in place on f16 H
__global__ void k_prep_ip(f16* __restrict__ hz, const float* __restrict__ sc,
                          const float* __restrict__ sh, int n8) {
    for (int i = blockIdx.x * blockDim.x + threadIdx.x; i < n8; i += gridDim.x * blockDim.x) {
        int c0 = (i & 15) * 8;
        f16x8 v = *(const f16x8*)&hz[(size_t)i * 8];
        float4 s0 = *(const float4*)&sc[c0];
        float4 s1 = *(const float4*)&sc[c0 + 4];
        float4 h0 = *(const float4*)&sh[c0];
        float4 h1 = *(const float4*)&sh[c0 + 4];
        v[0] = (f16)fmaxf((float)v[0] * s0.x + h0.x, 0.f);
        v[1] = (f16)fmaxf((float)v[1] * s0.y + h0.y, 0.f);
        v[2] = (f16)fmaxf((float)v[2] * s0.z + h0.z, 0.f);
        v[3] = (f16)fmaxf((float)v[3] * s0.w + h0.w, 0.f);
        v[4] = (f16)fmaxf((float)v[4] * s1.x + h1.x, 0.f);
        v[5] = (f16)fmaxf((float)v[5] * s1.y + h1.y, 0.f);
        v[6] = (f16)fmaxf((float)v[6] * s1.z + h1.z, 0.f);
        v[7] = (f16)fmaxf((float)v[7] * s1.w + h1.w, 0.f);
        *(f16x8*)&hz[(size_t)i * 8] = v;
    }
}

static __device__ __forceinline__ void acc_sum(f16x8 v, float* a) {
#pragma unroll
    for (int j = 0; j < 8; j++) a[j] += (float)v[j];
}

// ---------------------------------------------------------------- pool + MFMA GEMM1
// 512 threads = 8 waves. W fragments live in registers (no LDS W tile).
// Phase A: 1 row per 16-lane group -> LDS. Phase B: 32x128 @ 128x128 MFMA.
// Z output stored non-temporally (read once) to keep H resident in L3.
__global__ __launch_bounds__(512, 4) void k_pgemm(
    const f16* __restrict__ h, const int* __restrict__ row_ptr,
    const int* __restrict__ src_sorted, const float* __restrict__ eps, int li,
    const float* __restrict__ W, const float* __restrict__ bias,
    f16* __restrict__ out, float* __restrict__ gsum, float* __restrict__ gsq, int n) {
    __shared__ f16 Pl[32 * LDP];      // 8.7 KB
    __shared__ float red[8 * 256];    // 8 KB stats scratch
    const int t = threadIdx.x;
    const int lane = t & 63, w = t >> 6;          // 8 waves
    const int l15 = lane & 15, lq = lane >> 4;

    // wave w: rows rt..rt+15, col-tiles ct0, ct0+1
    const int rt = (w & 1) * 16;
    const int ct0 = (w >> 1) * 2;

    // W^T fragments in registers: wf[i][k0][j] = W[(k0*32+8*lq+j)*128 + (ct0+i)*16+l15]
    f16x8 wf[2][4];
#pragma unroll
    for (int i = 0; i < 2; i++)
#pragma unroll
        for (int k0 = 0; k0 < 4; k0++) {
            const int c = (ct0 + i) * 16 + l15;
            const int kb = k0 * 32 + 8 * lq;
            f16x8 v;
#pragma unroll
            for (int j = 0; j < 8; j++) v[j] = (f16)W[(size_t)(kb + j) * HD + c];
            wf[i][k0] = v;
        }
    float bv[2];
#pragma unroll
    for (int i = 0; i < 2; i++) bv[i] = bias[(ct0 + i) * 16 + l15];

    const int ga = t >> 4, ca = (t & 15) * 8;
    const float ep = 1.f + eps[li];

    float s8[8] = {0}, q8[8] = {0};
    const int ntiles = n / 32;
    for (int tile = blockIdx.x; tile < ntiles; tile += gridDim.x) {
        __syncthreads();
        // ---- Phase A: 1 row per 16-lane group, pure sum gather
        {
            const int r = tile * 32 + ga;
            float a[8];
            f16x8 u = *(const f16x8*)&h[(size_t)r * HD + ca];
#pragma unroll
            for (int j = 0; j < 8; j++) a[j] = ep * (float)u[j];
            const int j1 = row_ptr[r + 1];
            int j = row_ptr[r];
            for (; j + 3 < j1; j += 4) {
                int s0 = src_sorted[j], s1 = src_sorted[j + 1];
                int s2 = src_sorted[j + 2], s3 = src_sorted[j + 3];
                f16x8 v0 = *(const f16x8*)&h[(size_t)s0 * HD + ca];
                f16x8 v1 = *(const f16x8*)&h[(size_t)s1 * HD + ca];
                f16x8 v2 = *(const f16x8*)&h[(size_t)s2 * HD + ca];
                f16x8 v3 = *(const f16x8*)&h[(size_t)s3 * HD + ca];
                acc_sum(v0, a); acc_sum(v1, a); acc_sum(v2, a); acc_sum(v3, a);
            }
            for (; j < j1; j++) {
                f16x8 v = *(const f16x8*)&h[(size_t)src_sorted[j] * HD + ca];
                acc_sum(v, a);
            }
            f16x8 o;
#pragma unroll
            for (int jj = 0; jj < 8; jj++) o[jj] = (f16)a[jj];
            *(f16x8*)&Pl[ga * LDP + ca] = o;
        }
        __syncthreads();
        // ---- hoist A fragments
        f16x8 af[4];
#pragma unroll
        for (int k0 = 0; k0 < 4; k0++)
            af[k0] = *(const f16x8*)&Pl[(rt + l15) * LDP + k0 * 32 + 8 * lq];
        __syncthreads();
        // ---- MFMA (2 col-tiles) + writeback to Pl
#pragma unroll
        for (int i = 0; i < 2; i++) {
            f32x4 acc = {0.f, 0.f, 0.f, 0.f};
#pragma unroll
            for (int k0 = 0; k0 < 4; k0++)
                acc = __builtin_amdgcn_mfma_f32_16x16x32_f16(af[k0], wf[i][k0], acc, 0, 0, 0);
            const int c0 = (ct0 + i) * 16;
#pragma unroll
            for (int ri = 0; ri < 4; ri++)
                Pl[(rt + lq * 4 + ri) * LDP + c0 + l15] = (f16)(acc[ri] + bv[i]);
        }
        __syncthreads();
        // ---- epilogue: one f16x8 per thread, non-temporal store + stats
        {
            const int row = t >> 4;
            f16x8 v = *(const f16x8*)&Pl[row * LDP + ca];
            u32x4 v4 = *(u32x4*)&v;
            __builtin_nontemporal_store(v4, (u32x4*)&out[(size_t)(tile * 32 + row) * HD + ca]);
#pragma unroll
            for (int j = 0; j < 8; j++) {
                float f = (float)v[j];
                s8[j] += f; q8[j] += f * f;
            }
        }
    }

    // ---- stats: intra-wave shfl over lq, then LDS over waves
#pragma unroll
    for (int j = 0; j < 8; j++) {
        s8[j] += __shfl_xor(s8[j], 16, 64); s8[j] += __shfl_xor(s8[j], 32, 64);
        q8[j] += __shfl_xor(q8[j], 16, 64); q8[j] += __shfl_xor(q8[j], 32, 64);
    }
    if (lane < 16) {
#pragma unroll
        for (int j = 0; j < 8; j++) {
            red[w * 256 + l15 * 16 + j] = s8[j];
            red[w * 256 + l15 * 16 + 8 + j] = q8[j];
        }
    }
    __syncthreads();
    if (t < HD) {
        const int g = t >> 3, j = t & 7;
        float ts = 0.f, tq = 0.f;
#pragma unroll
        for (int i = 0; i < 8; i++) {
            ts += red[i * 256 + g * 16 + j];
            tq += red[i * 256 + g * 16 + 8 + j];
        }
        unsafeAtomicAdd(&gsum[t], ts);
        unsafeAtomicAdd(&gsq[t], tq);
    }
}

// ---------------------------------------------------------------- dense MFMA GEMM (n x 128)@(128 x 128)
// MODE 1: A = relu(f16(in)*tsc+tsh)  (nt loads: input read once)
// MODE 2: A = relu((p0[r]-mp)*tsc+tsh)
template <int MODE>
__global__ __launch_bounds__(256) void k_gemm(
    const void* __restrict__ in_, const float* __restrict__ W,
    const float* __restrict__ bias,
    const float* __restrict__ tsc, const float* __restrict__ tsh,
    const float* __restrict__ mstat,
    f16* __restrict__ out, float* __restrict__ gsum, float* __restrict__ gsq, int n) {
    __shared__ f16 Wl[HD * LDP];   // 34.8 KB
    __shared__ f16 Al[64 * LDP];   // 17.4 KB
    const int t = threadIdx.x;
    const int lane = t & 63, w = t >> 6;
    const int l15 = lane & 15, lq = lane >> 4;

    for (int p = 0; p < 64; p++) {
        int idx = p * 256 + t;
        Wl[(idx & 127) * LDP + (idx >> 7)] = (f16)W[idx];
    }

    const int ca = (t & 15) * 8;
    float tscv[8], tshv[8];
    *(float4*)&tscv[0] = *(const float4*)&tsc[ca];
    *(float4*)&tscv[4] = *(const float4*)&tsc[ca + 4];
    *(float4*)&tshv[0] = *(const float4*)&tsh[ca];
    *(float4*)&tshv[4] = *(const float4*)&tsh[ca + 4];
    float mp = 0.f;
    if (MODE == 2) mp = mstat[2];
    float bv[8];
#pragma unroll
    for (int ct = 0; ct < 8; ct++) bv[ct] = bias[ct * 16 + l15];

    const int r0 = w * 16;
    float s8[8] = {0}, q8[8] = {0};
    const int ntiles = n / 64;
    for (int tile = blockIdx.x; tile < ntiles; tile += gridDim.x) {
        __syncthreads();
#pragma unroll
        for (int p = 0; p < 4; p++) {
            const int row = (t >> 4) + p * 16;
            const int grow = tile * 64 + row;
            f16x8 o;
            if (MODE == 1) {
                u32x4 raw = __builtin_nontemporal_load(
                    (const u32x4*)&((const f16*)in_)[(size_t)grow * HD + ca]);
                f16x8 zv = *(f16x8*)&raw;
#pragma unroll
                for (int j = 0; j < 8; j++)
                    o[j] = (f16)fmaxf((float)zv[j] * tscv[j] + tshv[j], 0.f);
            } else {
                const float pr = ((const float*)in_)[grow] - mp;
#pragma unroll
                for (int j = 0; j < 8; j++)
                    o[j] = (f16)fmaxf(pr * tscv[j] + tshv[j], 0.f);
            }
            *(f16x8*)&Al[row * LDP + ca] = o;
        }
        __syncthreads();
        f16x8 af[4];
#pragma unroll
        for (int k0 = 0; k0 < 4; k0++)
            af[k0] = *(const f16x8*)&Al[(r0 + l15) * LDP + k0 * 32 + 8 * lq];
#pragma unroll
        for (int ct = 0; ct < 8; ct++) {
            f32x4 acc = {0.f, 0.f, 0.f, 0.f};
#pragma unroll
            for (int k0 = 0; k0 < 4; k0++) {
                f16x8 bf = *(const f16x8*)&Wl[(ct * 16 + l15) * LDP + k0 * 32 + 8 * lq];
                acc = __builtin_amdgcn_mfma_f32_16x16x32_f16(af[k0], bf, acc, 0, 0, 0);
            }
#pragma unroll
            for (int ri = 0; ri < 4; ri++)
                Al[(r0 + lq * 4 + ri) * LDP + ct * 16 + l15] = (f16)(acc[ri] + bv[ct]);
        }
        __syncthreads();
#pragma unroll
        for (int p = 0; p < 4; p++) {
            int row = (t >> 4) + p * 16;
            f16x8 v = *(const f16x8*)&Al[row * LDP + ca];
            *(f16x8*)&out[(size_t)(tile * 64 + row) * HD + ca] = v;
#pragma unroll
            for (int j = 0; j < 8; j++) {
                float f = (float)v[j];
                s8[j] += f; q8[j] += f * f;
            }
        }
    }

    __syncthreads();
    float* red = (float*)Al;
#pragma unroll
    for (int j = 0; j < 8; j++) { red[t * 16 + j] = s8[j]; red[t * 16 + 8 + j] = q8[j]; }
    __syncthreads();
    if (t < HD) {
        int g = t >> 3, j = t & 7;
        float ts = 0.f, tq = 0.f;
#pragma unroll
        for (int i = 0; i < 16; i++) {
            ts += red[(i * 16 + g) * 16 + j];
            tq += red[(i * 16 + g) * 16 + 8 + j];
        }
        unsafeAtomicAdd(&gsum[t], ts);
        unsafeAtomicAdd(&gsq[t], tq);
    }
}

// mean/var -> affine (sc, sh)
__global__ void k_finalize(const float* __restrict__ gsum, const float* __restrict__ gsq,
                           const float* __restrict__ g, const float* __restrict__ b,
                           float* __restrict__ sc, float* __restrict__ sh, int n) {
    int c = threadIdx.x;
    float m = gsum[c] / n;
    float v = gsq[c] / n - m * m;
    float s = rsqrtf(v + 1e-5f) * g[c];
    sc[c] = s;
    sh[c] = b[c] - m * s;
}

// classifier head (applies final BN affine itself), reads f16 z
__global__ void k_head(const unsigned short* __restrict__ z, const float* __restrict__ sc,
                       const float* __restrict__ sh, const float* __restrict__ fw,
                       const float* __restrict__ fb, float* __restrict__ out, int n) {
    int gid  = blockIdx.x * blockDim.x + threadIdx.x;
    int lane = threadIdx.x & 63;
    int w    = gid >> 6;
    int nw   = (gridDim.x * blockDim.x) >> 6;
    int c    = lane * 2;
    float s0 = sc[c], s1 = sc[c + 1], t0 = sh[c], t1 = sh[c + 1];
    float w00 = fw[c * 2], w01 = fw[c * 2 + 1], w10 = fw[c * 2 + 2], w11 = fw[c * 2 + 3];
    float fb0 = fb[0], fb1 = fb[1];
    for (int r = w; r < n; r += nw) {
        unsigned int u = *(const unsigned int*)&z[(size_t)r * HD + c];
        float zx = h2f((unsigned short)(u & 0xffffu));
        float zy = h2f((unsigned short)(u >> 16));
        float x0 = fmaxf(zx * s0 + t0, 0.f);
        float x1 = fmaxf(zy * s1 + t1, 0.f);
        float l0 = x0 * w00 + x1 * w10;
        float l1 = x0 * w01 + x1 * w11;
#pragma unroll
        for (int o = 32; o > 0; o >>= 1) {
            l0 += __shfl_xor(l0, o, 64);
            l1 += __shfl_xor(l1, o, 64);
        }
        if (lane == 0) {
            l0 += fb0; l1 += fb1;
            float m  = fmaxf(l0, l1);
            float e0 = expf(l0 - m), e1 = expf(l1 - m);
            float inv = 1.f / (e0 + e1);
            *(float2*)&out[(size_t)r * 2] = make_float2(e0 * inv, e1 * inv);
        }
    }
}

extern "C" void kernel_launch(void* const* d_in, const int* in_sizes, int n_in,
                              void* d_out, int out_size, void* d_ws, size_t ws_size,
                              hipStream_t stream) {
    const float* vf    = (const float*)d_in[1];
    const int*   src   = (const int*)d_in[2];
    const int*   dst   = (const int*)d_in[3];
    const float* eps   = (const float*)d_in[4];
    const float* W1_0  = (const float*)d_in[5];
    const float* g1_0  = (const float*)d_in[7];
    const float* bb1_0 = (const float*)d_in[8];
    const float* W2_0  = (const float*)d_in[9];
    const float* b2_0  = (const float*)d_in[10];
    const float* bn0g  = (const float*)d_in[11];
    const float* bn0b  = (const float*)d_in[12];
    const float* W1s   = (const float*)d_in[13];
    const float* b1s   = (const float*)d_in[14];
    const float* g1s   = (const float*)d_in[15];
    const float* bb1s  = (const float*)d_in[16];
    const float* W2s   = (const float*)d_in[17];
    const float* b2s   = (const float*)d_in[18];
    const float* bngs  = (const float*)d_in[19];
    const float* bnbs  = (const float*)d_in[20];
    const float* fw    = (const float*)d_in[21];
    const float* fb    = (const float*)d_in[22];
    float* out = (float*)d_out;

    const int N = in_sizes[1];  // 400000
    const int E = in_sizes[2];  // 6400000
    const int NB   = (N + CMSK) >> CSH;   // coarse buckets (98)
    const int NB32 = NB * NSUB;

    const size_t needed = (size_t)N * HD * 2 * 2 + (size_t)(N + 8 + 9 * 128 + 512) * 4
                        + (size_t)(2 * N + 1 + E) * 4 + (size_t)(2 * NB32 + 2) * 4;
    if (ws_size < needed) {
        float code = (float)(double)(ws_size >> 20);
        k_diag<<<2048, 256, 0, stream>>>(out, out_size, code);
        return;
    }

    f16* H            = (f16*)d_ws;                 // z2 raw -> activated in place
    f16* Z            = H + (size_t)N * HD;         // z1 raw (also aliased as CSR temp)
    float* p0         = (float*)(Z + (size_t)N * HD);
    float* stats      = p0 + N;
    float* gsum       = stats + 8;
    float* gsq        = gsum + HD;
    float* sc1        = gsq + HD;
    float* sh1        = sc1 + HD;
    float* sc2        = sh1 + HD;
    float* sh2        = sc2 + HD;
    float* A0         = sh2 + HD;
    float* Sh0        = A0 + HD;
    int* bsum         = (int*)(Sh0 + HD);  // 512
    int* row_ptr      = bsum + 512;        // N+1
    int* fill         = row_ptr + (N + 1); // N
    int* src_sorted   = fill + N;          // E
    int* ccnt         = src_sorted + E;    // NB32+1
    int* cfill        = ccnt + (NB32 + 1); // NB32
    int* tmp          = (int*)Z;           // E (aliases Z; free until layer 1)

    // -------- CSR build: two-level radix (coarse partition -> fine scatter)
    const int n1 = N + 1;
    const int nsb = (n1 + SCAN_B - 1) / SCAN_B;
    const int n2 = NB32 + 1;
    const int nsb2 = (n2 + SCAN_B - 1) / SCAN_B;
    k_zeroi<<<512, 256, 0, stream>>>(row_ptr, n1);
    k_zeroi<<<16, 256, 0, stream>>>(ccnt, n2);
    k_hist2<<<4096, 256, 0, stream>>>(dst, row_ptr, ccnt, E);
    k_scan_block<<<nsb, SCAN_B, 0, stream>>>(row_ptr, n1, bsum);
    k_scan_serial<<<1, 1, 0, stream>>>(bsum, nsb);
    k_scan_add<<<nsb, SCAN_B, 0, stream>>>(row_ptr, n1, bsum);
    k_scan_block<<<nsb2, SCAN_B, 0, stream>>>(ccnt, n2, bsum);
    k_scan_serial<<<1, 1, 0, stream>>>(bsum, nsb2);
    k_scan_add<<<nsb2, SCAN_B, 0, stream>>>(ccnt, n2, bsum);
    k_copyi<<<512, 256, 0, stream>>>(row_ptr, fill, N);
    k_copyi<<<16, 256, 0, stream>>>(ccnt, cfill, NB32);
    k_partition<<<4096, 256, 0, stream>>>(src, dst, cfill, tmp, E);
    k_bucket2<<<NB * 4, 256, 0, stream>>>(tmp, ccnt, fill, src_sorted);

    // -------- layer 0 (scalar features, rank-1 inner BN shortcut)
    k_pool0<<<2048, 256, 0, stream>>>(vf, row_ptr, src_sorted, eps, p0, N);
    k_zero<<<1, 256, 0, stream>>>(stats, 8);
    k_p0_stats<<<1024, 256, 0, stream>>>(p0, stats, N);
    k_l0_prep<<<1, 128, 0, stream>>>(stats, W1_0, g1_0, bb1_0, A0, Sh0, N);
    k_zero<<<1, 256, 0, stream>>>(gsum, 2 * HD);
    k_gemm<2><<<2048, 256, 0, stream>>>(p0, W2_0, b2_0, A0, Sh0, stats, H, gsum, gsq, N);
    k_finalize<<<1, 128, 0, stream>>>(gsum, gsq, bn0g, bn0b, sc2, sh2, N);

    // -------- layers 1..3
    for (int l = 0; l < 3; l++) {
        k_prep_ip<<<4096, 256, 0, stream>>>(H, sc2, sh2, N * (HD / 8));
        k_zero<<<1, 256, 0, stream>>>(gsum, 2 * HD);
        k_pgemm<<<2048, 512, 0, stream>>>(H, row_ptr, src_sorted, eps, l + 1,
                                          W1s + (size_t)l * HD * HD, b1s + l * HD,
                                          Z, gsum, gsq, N);
        k_finalize<<<1, 128, 0, stream>>>(gsum, gsq, g1s + l * HD, bb1s + l * HD, sc1, sh1, N);
        k_zero<<<1, 256, 0, stream>>>(gsum, 2 * HD);
        k_gemm<1><<<2048, 256, 0, stream>>>(Z, W2s + (size_t)l * HD * HD, b2s + l * HD,
                                            sc1, sh1, nullptr, H, gsum, gsq, N);
        k_finalize<<<1, 128, 0, stream>>>(gsum, gsq, bngs + l * HD, bnbs + l * HD, sc2, sh2, N);
    }

    // -------- classifier head + softmax
    k_head<<<4096, 256, 0, stream>>>((const unsigned short*)H, sc2, sh2, fw, fb, out, N);
}

// Round 10
// 2372.645 us; speedup vs baseline: 1.5161x; 1.5161x over previous
//
#include <hip/hip_runtime.h>
#include <math.h>

#define HD 128
#define LDP 136   // padded LDS row stride in f16 elems
#define CSH 12    // coarse bucket shift (4096 dst per bucket)
#define CMSK 4095
#define NSUB 32   // sub-streams per coarse bucket
#define SUBSH 11  // edge-index chunk shift for sub-stream assignment

typedef _Float16 f16;
typedef _Float16 f16x8 __attribute__((ext_vector_type(8)));
typedef float f32x4 __attribute__((ext_vector_type(4)));

static __device__ __forceinline__ float h2f(unsigned short s) {
    f16 v; __builtin_memcpy(&v, &s, 2); return (float)v;
}

// ---------------------------------------------------------------- diagnostic
__global__ void k_diag(float* __restrict__ out, int n, float val) {
    for (int i = blockIdx.x * blockDim.x + threadIdx.x; i < n; i += gridDim.x * blockDim.x)
        out[i] = val;
}

// ---------------------------------------------------------------- utility
__global__ void k_zero(float* __restrict__ p, int n) {
    for (int i = threadIdx.x; i < n; i += blockDim.x) p[i] = 0.f;
}
__global__ void k_zeroi(int* __restrict__ p, int n) {
    for (int i = blockIdx.x * blockDim.x + threadIdx.x; i < n; i += gridDim.x * blockDim.x)
        p[i] = 0;
}
__global__ void k_copyi(const int* __restrict__ a, int* __restrict__ b, int n) {
    for (int i = blockIdx.x * blockDim.x + threadIdx.x; i < n; i += gridDim.x * blockDim.x)
        b[i] = a[i];
}

// ---------------------------------------------------------------- CSR build (two-level radix)
// coarse (bucket,sub) counts via LDS histogram: one global atomic per counter
// per block instead of one per edge.
__global__ void k_chist(const int* __restrict__ dst, int* __restrict__ ccnt,
                        int e, int nb32) {
    __shared__ int lh[4096];
    for (int i = threadIdx.x; i < nb32; i += blockDim.x) lh[i] = 0;
    __syncthreads();
    for (int i = blockIdx.x * blockDim.x + threadIdx.x; i < e; i += gridDim.x * blockDim.x) {
        int d = dst[i];
        atomicAdd(&lh[(d >> CSH) * NSUB + ((i >> SUBSH) & (NSUB - 1))], 1);
    }
    __syncthreads();
    for (int i = threadIdx.x; i < nb32; i += blockDim.x)
        if (lh[i]) atomicAdd(&ccnt[i + 1], lh[i]);
}

#define SCAN_B 1024
__global__ void k_scan_block(int* __restrict__ a, int n, int* __restrict__ bsum) {
    __shared__ int s[SCAN_B];
    int base = blockIdx.x * SCAN_B;
    int i = base + threadIdx.x;
    int v = (i < n) ? a[i] : 0;
    s[threadIdx.x] = v;
    __syncthreads();
    for (int o = 1; o < SCAN_B; o <<= 1) {
        int t = (threadIdx.x >= o) ? s[threadIdx.x - o] : 0;
        __syncthreads();
        s[threadIdx.x] += t;
        __syncthreads();
    }
    if (i < n) a[i] = s[threadIdx.x];
    if (threadIdx.x == 0) bsum[blockIdx.x] = s[SCAN_B - 1];
}
__global__ void k_scan_serial(int* __restrict__ bsum, int nb) {
    int run = 0;
    for (int b = 0; b < nb; b++) { int t = bsum[b]; bsum[b] = run; run += t; }
}
__global__ void k_scan_add(int* __restrict__ a, int n, const int* __restrict__ bsum) {
    int base = blockIdx.x * SCAN_B;
    int i = base + threadIdx.x;
    if (i < n) a[i] += bsum[blockIdx.x];
}

// pass 1: partition edges into (bucket,sub) sequential streams.
// entry = (src<<12) | (dst&4095); src < 2^19 so this fits 31 bits.
__global__ void k_partition(const int* __restrict__ src, const int* __restrict__ dst,
                            int* __restrict__ cfill, int* __restrict__ tmp, int e) {
    for (int i = blockIdx.x * blockDim.x + threadIdx.x; i < e; i += gridDim.x * blockDim.x) {
        int d = dst[i];
        int pos = atomicAdd(&cfill[(d >> CSH) * NSUB + ((i >> SUBSH) & (NSUB - 1))], 1);
        tmp[pos] = (src[i] << CSH) | (d & CMSK);
    }
}

// pass 2: one block per bucket: LDS histogram -> LDS scan -> coalesced row_ptr
// write -> LDS-counter scatter into contiguous (L2-resident) src_sorted region.
__global__ __launch_bounds__(1024) void k_build(const int* __restrict__ tmp,
                                                const int* __restrict__ ccnt,
                                                int* __restrict__ row_ptr,
                                                int* __restrict__ src_sorted,
                                                int n, int e, int nb) {
    __shared__ int lh[4096];
    __shared__ int part[1024];
    const int b = blockIdx.x;
    const int t = threadIdx.x;
    const int lo = ccnt[b * NSUB], hi = ccnt[(b + 1) * NSUB];
    for (int i = t; i < 4096; i += 1024) lh[i] = 0;
    __syncthreads();
    for (int i = lo + t; i < hi; i += 1024)
        atomicAdd(&lh[tmp[i] & CMSK], 1);
    __syncthreads();
    // exclusive scan of lh[4096]: 4 per thread + block scan of partials
    const int base4 = t * 4;
    int a0 = lh[base4], a1 = lh[base4 + 1], a2 = lh[base4 + 2], a3 = lh[base4 + 3];
    int tsum = a0 + a1 + a2 + a3;
    part[t] = tsum;
    __syncthreads();
    for (int o = 1; o < 1024; o <<= 1) {
        int tv = (t >= o) ? part[t - o] : 0;
        __syncthreads();
        part[t] += tv;
        __syncthreads();
    }
    int off = part[t] - tsum;
    lh[base4] = off;
    lh[base4 + 1] = off + a0;
    lh[base4 + 2] = off + a0 + a1;
    lh[base4 + 3] = off + a0 + a1 + a2;
    __syncthreads();
    // row_ptr slice, coalesced
    for (int d0 = t; d0 < 4096; d0 += 1024) {
        int gd = (b << CSH) + d0;
        if (gd < n) row_ptr[gd] = lo + lh[d0];
    }
    if (b == nb - 1 && t == 0) row_ptr[n] = e;
    __syncthreads();
    // scatter: lh now acts as per-dst fill counters
    for (int i = lo + t; i < hi; i += 1024) {
        int e2 = tmp[i];
        int pos = lo + atomicAdd(&lh[e2 & CMSK], 1);
        src_sorted[pos] = ((unsigned int)e2) >> CSH;
    }
}

// ---------------------------------------------------------------- layer 0
__global__ void k_pool0(const float* __restrict__ vf, const int* __restrict__ row_ptr,
                        const int* __restrict__ srcs, const float* __restrict__ eps,
                        float* __restrict__ p0, int n) {
    float ep = 1.f + eps[0];
    for (int i = blockIdx.x * blockDim.x + threadIdx.x; i < n; i += gridDim.x * blockDim.x) {
        float s = ep * vf[i];
        int j1 = row_ptr[i + 1];
        for (int j = row_ptr[i]; j < j1; j++) s += vf[srcs[j]];
        p0[i] = s;
    }
}

__global__ void k_p0_stats(const float* __restrict__ p0, float* __restrict__ stats, int n) {
    __shared__ float rs[256], rq[256];
    float s = 0.f, q = 0.f;
    for (int i = blockIdx.x * blockDim.x + threadIdx.x; i < n; i += gridDim.x * blockDim.x) {
        float v = p0[i]; s += v; q += v * v;
    }
    int t = threadIdx.x;
    rs[t] = s; rq[t] = q;
    __syncthreads();
    for (int o = 128; o > 0; o >>= 1) {
        if (t < o) { rs[t] += rs[t + o]; rq[t] += rq[t + o]; }
        __syncthreads();
    }
    if (t == 0) { unsafeAtomicAdd(&stats[0], rs[0]); unsafeAtomicAdd(&stats[1], rq[0]); }
}

__global__ void k_l0_prep(float* __restrict__ stats, const float* __restrict__ W1,
                          const float* __restrict__ g1, const float* __restrict__ bb1,
                          float* __restrict__ A0, float* __restrict__ Sh0, int n) {
    float mp = stats[0] / n;
    float vp = stats[1] / n - mp * mp;
    int c = threadIdx.x;
    float w = W1[c];
    A0[c] = w * rsqrtf(vp * w * w + 1e-5f) * g1[c];
    Sh0[c] = bb1[c];
    if (c == 0) stats[2] = mp;
}

// ---------------------------------------------------------------- BN+ReLU in place on f16 H
__global__ void k_prep_ip(f16* __restrict__ hz, const float* __restrict__ sc,
                          const float* __restrict__ sh, int n8) {
    for (int i = blockIdx.x * blockDim.x + threadIdx.x; i < n8; i += gridDim.x * blockDim.x) {
        int c0 = (i & 15) * 8;
        f16x8 v = *(const f16x8*)&hz[(size_t)i * 8];
        float4 s0 = *(const float4*)&sc[c0];
        float4 s1 = *(const float4*)&sc[c0 + 4];
        float4 h0 = *(const float4*)&sh[c0];
        float4 h1 = *(const float4*)&sh[c0 + 4];
        v[0] = (f16)fmaxf((float)v[0] * s0.x + h0.x, 0.f);
        v[1] = (f16)fmaxf((float)v[1] * s0.y + h0.y, 0.f);
        v[2] = (f16)fmaxf((float)v[2] * s0.z + h0.z, 0.f);
        v[3] = (f16)fmaxf((float)v[3] * s0.w + h0.w, 0.f);
        v[4] = (f16)fmaxf((float)v[4] * s1.x + h1.x, 0.f);
        v[5] = (f16)fmaxf((float)v[5] * s1.y + h1.y, 0.f);
        v[6] = (f16)fmaxf((float)v[6] * s1.z + h1.z, 0.f);
        v[7] = (f16)fmaxf((float)v[7] * s1.w + h1.w, 0.f);
        *(f16x8*)&hz[(size_t)i * 8] = v;
    }
}

static __device__ __forceinline__ void acc_sum(f16x8 v, float* a) {
#pragma unroll
    for (int j = 0; j < 8; j++) a[j] += (float)v[j];
}

// ---------------------------------------------------------------- pool + MFMA GEMM1 (R8 measured-good)
__global__ __launch_bounds__(256) void k_pgemm(
    const f16* __restrict__ h, const int* __restrict__ row_ptr,
    const int* __restrict__ src_sorted, const float* __restrict__ eps, int li,
    const float* __restrict__ W, const float* __restrict__ bias,
    f16* __restrict__ out, float* __restrict__ gsum, float* __restrict__ gsq, int n) {
    __shared__ f16 Wl[HD * LDP];   // W^T [c][k], 34.8 KB
    __shared__ f16 Pl[32 * LDP];   // pooled tile [r][c], 8.7 KB
    const int t = threadIdx.x;
    const int lane = t & 63, w = t >> 6;
    const int l15 = lane & 15, lq = lane >> 4;

    for (int p = 0; p < 64; p++) {
        int idx = p * 256 + t;
        Wl[(idx & 127) * LDP + (idx >> 7)] = (f16)W[idx];
    }

    const int ga = t >> 4, ca = (t & 15) * 8;
    const float ep = 1.f + eps[li];

    const int rt = (w & 1) * 16;
    const int ctb = (w >> 1) * 4;
    float bv[4];
#pragma unroll
    for (int i = 0; i < 4; i++) bv[i] = bias[(ctb + i) * 16 + l15];

    float s8[8] = {0}, q8[8] = {0};
    const int ntiles = n / 32;
    for (int tile = blockIdx.x; tile < ntiles; tile += gridDim.x) {
        __syncthreads();
        // ---- Phase A: 2 rows per 16-lane group, pure sum gather
#pragma unroll
        for (int rr = 0; rr < 2; rr++) {
            const int r = tile * 32 + ga * 2 + rr;
            float a[8];
            {
                f16x8 u = *(const f16x8*)&h[(size_t)r * HD + ca];
#pragma unroll
                for (int j = 0; j < 8; j++) a[j] = ep * (float)u[j];
            }
            const int j0 = row_ptr[r], j1 = row_ptr[r + 1];
            int j = j0;
            for (; j + 3 < j1; j += 4) {
                int s0 = src_sorted[j], s1 = src_sorted[j + 1];
                int s2 = src_sorted[j + 2], s3 = src_sorted[j + 3];
                f16x8 v0 = *(const f16x8*)&h[(size_t)s0 * HD + ca];
                f16x8 v1 = *(const f16x8*)&h[(size_t)s1 * HD + ca];
                f16x8 v2 = *(const f16x8*)&h[(size_t)s2 * HD + ca];
                f16x8 v3 = *(const f16x8*)&h[(size_t)s3 * HD + ca];
                acc_sum(v0, a); acc_sum(v1, a); acc_sum(v2, a); acc_sum(v3, a);
            }
            for (; j < j1; j++) {
                f16x8 v = *(const f16x8*)&h[(size_t)src_sorted[j] * HD + ca];
                acc_sum(v, a);
            }
            f16x8 o;
#pragma unroll
            for (int jj = 0; jj < 8; jj++) o[jj] = (f16)a[jj];
            *(f16x8*)&Pl[(ga * 2 + rr) * LDP + ca] = o;
        }
        __syncthreads();
        f16x8 af[4];
#pragma unroll
        for (int k0 = 0; k0 < 4; k0++)
            af[k0] = *(const f16x8*)&Pl[(rt + l15) * LDP + k0 * 32 + 8 * lq];
        __syncthreads();
#pragma unroll
        for (int i = 0; i < 4; i++) {
            f32x4 acc = {0.f, 0.f, 0.f, 0.f};
            const int c0 = (ctb + i) * 16;
#pragma unroll
            for (int k0 = 0; k0 < 4; k0++) {
                f16x8 bf = *(const f16x8*)&Wl[(c0 + l15) * LDP + k0 * 32 + 8 * lq];
                acc = __builtin_amdgcn_mfma_f32_16x16x32_f16(af[k0], bf, acc, 0, 0, 0);
            }
#pragma unroll
            for (int ri = 0; ri < 4; ri++)
                Pl[(rt + lq * 4 + ri) * LDP + c0 + l15] = (f16)(acc[ri] + bv[i]);
        }
        __syncthreads();
#pragma unroll
        for (int p = 0; p < 2; p++) {
            int u = p * 256 + t;
            int row = u >> 4;
            f16x8 v = *(const f16x8*)&Pl[row * LDP + ca];
            *(f16x8*)&out[(size_t)(tile * 32 + row) * HD + ca] = v;
#pragma unroll
            for (int j = 0; j < 8; j++) {
                float f = (float)v[j];
                s8[j] += f; q8[j] += f * f;
            }
        }
    }

    __syncthreads();
    float* red = (float*)Wl;
#pragma unroll
    for (int j = 0; j < 8; j++) { red[t * 16 + j] = s8[j]; red[t * 16 + 8 + j] = q8[j]; }
    __syncthreads();
    if (t < HD) {
        int g = t >> 3, j = t & 7;
        float ts = 0.f, tq = 0.f;
#pragma unroll
        for (int i = 0; i < 16; i++) {
            ts += red[(i * 16 + g) * 16 + j];
            tq += red[(i * 16 + g) * 16 + 8 + j];
        }
        unsafeAtomicAdd(&gsum[t], ts);
        unsafeAtomicAdd(&gsq[t], tq);
    }
}

// ---------------------------------------------------------------- dense MFMA GEMM (n x 128)@(128 x 128)
template <int MODE>
__global__ __launch_bounds__(256) void k_gemm(
    const void* __restrict__ in_, const float* __restrict__ W,
    const float* __restrict__ bias,
    const float* __restrict__ tsc, const float* __restrict__ tsh,
    const float* __restrict__ mstat,
    f16* __restrict__ out, float* __restrict__ gsum, float* __restrict__ gsq, int n) {
    __shared__ f16 Wl[HD * LDP];   // 34.8 KB
    __shared__ f16 Al[64 * LDP];   // 17.4 KB
    const int t = threadIdx.x;
    const int lane = t & 63, w = t >> 6;
    const int l15 = lane & 15, lq = lane >> 4;

    for (int p = 0; p < 64; p++) {
        int idx = p * 256 + t;
        Wl[(idx & 127) * LDP + (idx >> 7)] = (f16)W[idx];
    }

    const int ca = (t & 15) * 8;
    float tscv[8], tshv[8];
    *(float4*)&tscv[0] = *(const float4*)&tsc[ca];
    *(float4*)&tscv[4] = *(const float4*)&tsc[ca + 4];
    *(float4*)&tshv[0] = *(const float4*)&tsh[ca];
    *(float4*)&tshv[4] = *(const float4*)&tsh[ca + 4];
    float mp = 0.f;
    if (MODE == 2) mp = mstat[2];
    float bv[8];
#pragma unroll
    for (int ct = 0; ct < 8; ct++) bv[ct] = bias[ct * 16 + l15];

    const int r0 = w * 16;
    float s8[8] = {0}, q8[8] = {0};
    const int ntiles = n / 64;
    for (int tile = blockIdx.x; tile < ntiles; tile += gridDim.x) {
        __syncthreads();
#pragma unroll
        for (int p = 0; p < 4; p++) {
            const int row = (t >> 4) + p * 16;
            const int grow = tile * 64 + row;
            f16x8 o;
            if (MODE == 1) {
                f16x8 zv = *(const f16x8*)&((const f16*)in_)[(size_t)grow * HD + ca];
#pragma unroll
                for (int j = 0; j < 8; j++)
                    o[j] = (f16)fmaxf((float)zv[j] * tscv[j] + tshv[j], 0.f);
            } else {
                const float pr = ((const float*)in_)[grow] - mp;
#pragma unroll
                for (int j = 0; j < 8; j++)
                    o[j] = (f16)fmaxf(pr * tscv[j] + tshv[j], 0.f);
            }
            *(f16x8*)&Al[row * LDP + ca] = o;
        }
        __syncthreads();
        f16x8 af[4];
#pragma unroll
        for (int k0 = 0; k0 < 4; k0++)
            af[k0] = *(const f16x8*)&Al[(r0 + l15) * LDP + k0 * 32 + 8 * lq];
#pragma unroll
        for (int ct = 0; ct < 8; ct++) {
            f32x4 acc = {0.f, 0.f, 0.f, 0.f};
#pragma unroll
            for (int k0 = 0; k0 < 4; k0++) {
                f16x8 bf = *(const f16x8*)&Wl[(ct * 16 + l15) * LDP + k0 * 32 + 8 * lq];
                acc = __builtin_amdgcn_mfma_f32_16x16x32_f16(af[k0], bf, acc, 0, 0, 0);
            }
#pragma unroll
            for (int ri = 0; ri < 4; ri++)
                Al[(r0 + lq * 4 + ri) * LDP + ct * 16 + l15] = (f16)(acc[ri] + bv[ct]);
        }
        __syncthreads();
#pragma unroll
        for (int p = 0; p < 4; p++) {
            int row = (t >> 4) + p * 16;
            f16x8 v = *(const f16x8*)&Al[row * LDP + ca];
            *(f16x8*)&out[(size_t)(tile * 64 + row) * HD + ca] = v;
#pragma unroll
            for (int j = 0; j < 8; j++) {
                float f = (float)v[j];
                s8[j] += f; q8[j] += f * f;
            }
        }
    }

    __syncthreads();
    float* red = (float*)Al;
#pragma unroll
    for (int j = 0; j < 8; j++) { red[t * 16 + j] = s8[j]; red[t * 16 + 8 + j] = q8[j]; }
    __syncthreads();
    if (t < HD) {
        int g = t >> 3, j = t & 7;
        float ts = 0.f, tq = 0.f;
#pragma unroll
        for (int i = 0; i < 16; i++) {
            ts += red[(i * 16 + g) * 16 + j];
            tq += red[(i * 16 + g) * 16 + 8 + j];
        }
        unsafeAtomicAdd(&gsum[t], ts);
        unsafeAtomicAdd(&gsq[t], tq);
    }
}

// mean/var -> affine (sc, sh)
__global__ void k_finalize(const float* __restrict__ gsum, const float* __restrict__ gsq,
                           const float* __restrict__ g, const float* __restrict__ b,
                           float* __restrict__ sc, float* __restrict__ sh, int n) {
    int c = threadIdx.x;
    float m = gsum[c] / n;
    float v = gsq[c] / n - m * m;
    float s = rsqrtf(v + 1e-5f) * g[c];
    sc[c] = s;
    sh[c] = b[c] - m * s;
}

// classifier head (applies final BN affine itself), reads f16 z
__global__ void k_head(const unsigned short* __restrict__ z, const float* __restrict__ sc,
                       const float* __restrict__ sh, const float* __restrict__ fw,
                       const float* __restrict__ fb, float* __restrict__ out, int n) {
    int gid  = blockIdx.x * blockDim.x + threadIdx.x;
    int lane = threadIdx.x & 63;
    int w    = gid >> 6;
    int nw   = (gridDim.x * blockDim.x) >> 6;
    int c    = lane * 2;
    float s0 = sc[c], s1 = sc[c + 1], t0 = sh[c], t1 = sh[c + 1];
    float w00 = fw[c * 2], w01 = fw[c * 2 + 1], w10 = fw[c * 2 + 2], w11 = fw[c * 2 + 3];
    float fb0 = fb[0], fb1 = fb[1];
    for (int r = w; r < n; r += nw) {
        unsigned int u = *(const unsigned int*)&z[(size_t)r * HD + c];
        float zx = h2f((unsigned short)(u & 0xffffu));
        float zy = h2f((unsigned short)(u >> 16));
        float x0 = fmaxf(zx * s0 + t0, 0.f);
        float x1 = fmaxf(zy * s1 + t1, 0.f);
        float l0 = x0 * w00 + x1 * w10;
        float l1 = x0 * w01 + x1 * w11;
#pragma unroll
        for (int o = 32; o > 0; o >>= 1) {
            l0 += __shfl_xor(l0, o, 64);
            l1 += __shfl_xor(l1, o, 64);
        }
        if (lane == 0) {
            l0 += fb0; l1 += fb1;
            float m  = fmaxf(l0, l1);
            float e0 = expf(l0 - m), e1 = expf(l1 - m);
            float inv = 1.f / (e0 + e1);
            *(float2*)&out[(size_t)r * 2] = make_float2(e0 * inv, e1 * inv);
        }
    }
}

extern "C" void kernel_launch(void* const* d_in, const int* in_sizes, int n_in,
                              void* d_out, int out_size, void* d_ws, size_t ws_size,
                              hipStream_t stream) {
    const float* vf    = (const float*)d_in[1];
    const int*   src   = (const int*)d_in[2];
    const int*   dst   = (const int*)d_in[3];
    const float* eps   = (const float*)d_in[4];
    const float* W1_0  = (const float*)d_in[5];
    const float* g1_0  = (const float*)d_in[7];
    const float* bb1_0 = (const float*)d_in[8];
    const float* W2_0  = (const float*)d_in[9];
    const float* b2_0  = (const float*)d_in[10];
    const float* bn0g  = (const float*)d_in[11];
    const float* bn0b  = (const float*)d_in[12];
    const float* W1s   = (const float*)d_in[13];
    const float* b1s   = (const float*)d_in[14];
    const float* g1s   = (const float*)d_in[15];
    const float* bb1s  = (const float*)d_in[16];
    const float* W2s   = (const float*)d_in[17];
    const float* b2s   = (const float*)d_in[18];
    const float* bngs  = (const float*)d_in[19];
    const float* bnbs  = (const float*)d_in[20];
    const float* fw    = (const float*)d_in[21];
    const float* fb    = (const float*)d_in[22];
    float* out = (float*)d_out;

    const int N = in_sizes[1];  // 400000
    const int E = in_sizes[2];  // 6400000
    const int NB   = (N + CMSK) >> CSH;   // coarse buckets (98)
    const int NB32 = NB * NSUB;           // 3136 (must be <= 4096 for LDS hist)

    const size_t needed = (size_t)N * HD * 2 * 2 + (size_t)(N + 8 + 9 * 128 + 512) * 4
                        + (size_t)(N + 1 + E) * 4 + (size_t)(2 * NB32 + 2) * 4;
    if (ws_size < needed || NB32 > 4096) {
        float code = (float)(double)(ws_size >> 20);
        k_diag<<<2048, 256, 0, stream>>>(out, out_size, code);
        return;
    }

    f16* H            = (f16*)d_ws;                 // z2 raw -> activated in place
    f16* Z            = H + (size_t)N * HD;         // z1 raw (also aliased as CSR temp)
    float* p0         = (float*)(Z + (size_t)N * HD);
    float* stats      = p0 + N;
    float* gsum       = stats + 8;
    float* gsq        = gsum + HD;
    float* sc1        = gsq + HD;
    float* sh1        = sc1 + HD;
    float* sc2        = sh1 + HD;
    float* sh2        = sc2 + HD;
    float* A0         = sh2 + HD;
    float* Sh0        = A0 + HD;
    int* bsum         = (int*)(Sh0 + HD);  // 512
    int* row_ptr      = bsum + 512;        // N+1
    int* src_sorted   = row_ptr + (N + 1); // E
    int* ccnt         = src_sorted + E;    // NB32+1
    int* cfill        = ccnt + (NB32 + 1); // NB32
    int* tmp          = (int*)Z;           // E (aliases Z; free until layer 1)

    // -------- CSR build: LDS-hist coarse counts -> partition -> per-bucket build
    const int n2 = NB32 + 1;
    const int nsb2 = (n2 + SCAN_B - 1) / SCAN_B;
    k_zeroi<<<16, 256, 0, stream>>>(ccnt, n2);
    k_chist<<<256, 256, 0, stream>>>(dst, ccnt, E, NB32);
    k_scan_block<<<nsb2, SCAN_B, 0, stream>>>(ccnt, n2, bsum);
    k_scan_serial<<<1, 1, 0, stream>>>(bsum, nsb2);
    k_scan_add<<<nsb2, SCAN_B, 0, stream>>>(ccnt, n2, bsum);
    k_copyi<<<16, 256, 0, stream>>>(ccnt, cfill, NB32);
    k_partition<<<4096, 256, 0, stream>>>(src, dst, cfill, tmp, E);
    k_build<<<NB, 1024, 0, stream>>>(tmp, ccnt, row_ptr, src_sorted, N, E, NB);

    // -------- layer 0 (scalar features, rank-1 inner BN shortcut)
    k_pool0<<<2048, 256, 0, stream>>>(vf, row_ptr, src_sorted, eps, p0, N);
    k_zero<<<1, 256, 0, stream>>>(stats, 8);
    k_p0_stats<<<1024, 256, 0, stream>>>(p0, stats, N);
    k_l0_prep<<<1, 128, 0, stream>>>(stats, W1_0, g1_0, bb1_0, A0, Sh0, N);
    k_zero<<<1, 256, 0, stream>>>(gsum, 2 * HD);
    k_gemm<2><<<2048, 256, 0, stream>>>(p0, W2_0, b2_0, A0, Sh0, stats, H, gsum, gsq, N);
    k_finalize<<<1, 128, 0, stream>>>(gsum, gsq, bn0g, bn0b, sc2, sh2, N);

    // -------- layers 1..3
    for (int l = 0; l < 3; l++) {
        k_prep_ip<<<4096, 256, 0, stream>>>(H, sc2, sh2, N * (HD / 8));
        k_zero<<<1, 256, 0, stream>>>(gsum, 2 * HD);
        k_pgemm<<<2048, 256, 0, stream>>>(H, row_ptr, src_sorted, eps, l + 1,
                                          W1s + (size_t)l * HD * HD, b1s + l * HD,
                                          Z, gsum, gsq, N);
        k_finalize<<<1, 128, 0, stream>>>(gsum, gsq, g1s + l * HD, bb1s + l * HD, sc1, sh1, N);
        k_zero<<<1, 256, 0, stream>>>(gsum, 2 * HD);
        k_gemm<1><<<2048, 256, 0, stream>>>(Z, W2s + (size_t)l * HD * HD, b2s + l * HD,
                                            sc1, sh1, nullptr, H, gsum, gsq, N);
        k_finalize<<<1, 128, 0, stream>>>(gsum, gsq, bngs + l * HD, bnbs + l * HD, sc2, sh2, N);
    }

    // -------- classifier head + softmax
    k_head<<<4096, 256, 0, stream>>>((const unsigned short*)H, sc2, sh2, fw, fb, out, N);
}

// Round 11
// 1802.699 us; speedup vs baseline: 1.9955x; 1.3162x over previous
//
#include <hip/hip_runtime.h>
#include <math.h>

#define HD 128
#define LDP 136   // padded LDS row stride in f16 elems
#define CSH 12    // coarse bucket shift (4096 dst per bucket)
#define CMSK 4095
#define CHSH 13   // 8192 edges per partition chunk
#define CHSZ 8192

typedef _Float16 f16;
typedef _Float16 f16x8 __attribute__((ext_vector_type(8)));
typedef float f32x4 __attribute__((ext_vector_type(4)));

static __device__ __forceinline__ float h2f(unsigned short s) {
    f16 v; __builtin_memcpy(&v, &s, 2); return (float)v;
}

// ---------------------------------------------------------------- diagnostic
__global__ void k_diag(float* __restrict__ out, int n, float val) {
    for (int i = blockIdx.x * blockDim.x + threadIdx.x; i < n; i += gridDim.x * blockDim.x)
        out[i] = val;
}

// ---------------------------------------------------------------- utility
__global__ void k_zero(float* __restrict__ p, int n) {
    for (int i = threadIdx.x; i < n; i += blockDim.x) p[i] = 0.f;
}
__global__ void k_zeroi(int* __restrict__ p, int n) {
    for (int i = blockIdx.x * blockDim.x + threadIdx.x; i < n; i += gridDim.x * blockDim.x)
        p[i] = 0;
}

// ---------------------------------------------------------------- CSR build (chunk-owned counting sort)
// per-chunk LDS histogram of coarse buckets; counts[bucket][chunk] layout so the
// scanned offsets give bucket-contiguous, chunk-ordered regions.
__global__ __launch_bounds__(256) void k_cnt(const int* __restrict__ dst,
                                             int* __restrict__ ccnt,
                                             int e, int nchunks, int nbuk) {
    __shared__ int lh[128];
    const int c = blockIdx.x;
    const int base = c << CHSH;
    const int hi = min(base + CHSZ, e);
    for (int i = threadIdx.x; i < 128; i += 256) lh[i] = 0;
    __syncthreads();
    for (int i = base + threadIdx.x; i < hi; i += 256)
        atomicAdd(&lh[dst[i] >> CSH], 1);
    __syncthreads();
    for (int b = threadIdx.x; b < 128; b += 256)
        if (b < nbuk && lh[b]) ccnt[(b * nchunks + c) + 1] = lh[b];
}

#define SCAN_B 1024
__global__ void k_scan_block(int* __restrict__ a, int n, int* __restrict__ bsum) {
    __shared__ int s[SCAN_B];
    int base = blockIdx.x * SCAN_B;
    int i = base + threadIdx.x;
    int v = (i < n) ? a[i] : 0;
    s[threadIdx.x] = v;
    __syncthreads();
    for (int o = 1; o < SCAN_B; o <<= 1) {
        int t = (threadIdx.x >= o) ? s[threadIdx.x - o] : 0;
        __syncthreads();
        s[threadIdx.x] += t;
        __syncthreads();
    }
    if (i < n) a[i] = s[threadIdx.x];
    if (threadIdx.x == 0) bsum[blockIdx.x] = s[SCAN_B - 1];
}
__global__ void k_scan_serial(int* __restrict__ bsum, int nb) {
    int run = 0;
    for (int b = 0; b < nb; b++) { int t = bsum[b]; bsum[b] = run; run += t; }
}
__global__ void k_scan_add(int* __restrict__ a, int n, const int* __restrict__ bsum) {
    int base = blockIdx.x * SCAN_B;
    int i = base + threadIdx.x;
    if (i < n) a[i] += bsum[blockIdx.x];
}

// partition: one block per chunk; every (bucket,chunk) output region is written
// exclusively by this block -> cache lines fill before eviction.
// entry = (src<<12) | (dst&4095)
__global__ __launch_bounds__(256) void k_part2(const int* __restrict__ src,
                                               const int* __restrict__ dst,
                                               const int* __restrict__ ccnt,
                                               int* __restrict__ tmp,
                                               int e, int nchunks, int nbuk) {
    __shared__ int lh[128];
    const int c = blockIdx.x;
    const int base = c << CHSH;
    const int hi = min(base + CHSZ, e);
    for (int b = threadIdx.x; b < 128; b += 256)
        lh[b] = (b < nbuk) ? ccnt[b * nchunks + c] : 0;
    __syncthreads();
    for (int i = base + threadIdx.x; i < hi; i += 256) {
        int d = dst[i];
        int pos = atomicAdd(&lh[d >> CSH], 1);
        tmp[pos] = (src[i] << CSH) | (d & CMSK);
    }
}

// per-bucket fine build: LDS histogram -> LDS scan -> coalesced row_ptr ->
// LDS-counter scatter into the bucket's contiguous (L2-resident) region.
__global__ __launch_bounds__(1024) void k_build(const int* __restrict__ tmp,
                                                const int* __restrict__ ccnt,
                                                int* __restrict__ row_ptr,
                                                int* __restrict__ src_sorted,
                                                int n, int e, int nb, int stride) {
    __shared__ int lh[4096];
    __shared__ int part[1024];
    const int b = blockIdx.x;
    const int t = threadIdx.x;
    const int lo = ccnt[b * stride], hi = ccnt[(b + 1) * stride];
    for (int i = t; i < 4096; i += 1024) lh[i] = 0;
    __syncthreads();
    for (int i = lo + t; i < hi; i += 1024)
        atomicAdd(&lh[tmp[i] & CMSK], 1);
    __syncthreads();
    const int base4 = t * 4;
    int a0 = lh[base4], a1 = lh[base4 + 1], a2 = lh[base4 + 2], a3 = lh[base4 + 3];
    int tsum = a0 + a1 + a2 + a3;
    part[t] = tsum;
    __syncthreads();
    for (int o = 1; o < 1024; o <<= 1) {
        int tv = (t >= o) ? part[t - o] : 0;
        __syncthreads();
        part[t] += tv;
        __syncthreads();
    }
    int off = part[t] - tsum;
    lh[base4] = off;
    lh[base4 + 1] = off + a0;
    lh[base4 + 2] = off + a0 + a1;
    lh[base4 + 3] = off + a0 + a1 + a2;
    __syncthreads();
    for (int d0 = t; d0 < 4096; d0 += 1024) {
        int gd = (b << CSH) + d0;
        if (gd < n) row_ptr[gd] = lo + lh[d0];
    }
    if (b == nb - 1 && t == 0) row_ptr[n] = e;
    __syncthreads();
    for (int i = lo + t; i < hi; i += 1024) {
        int e2 = tmp[i];
        int pos = lo + atomicAdd(&lh[e2 & CMSK], 1);
        src_sorted[pos] = ((unsigned int)e2) >> CSH;
    }
}

// ---------------------------------------------------------------- layer 0
__global__ void k_pool0(const float* __restrict__ vf, const int* __restrict__ row_ptr,
                        const int* __restrict__ srcs, const float* __restrict__ eps,
                        float* __restrict__ p0, int n) {
    float ep = 1.f + eps[0];
    for (int i = blockIdx.x * blockDim.x + threadIdx.x; i < n; i += gridDim.x * blockDim.x) {
        float s = ep * vf[i];
        int j1 = row_ptr[i + 1];
        for (int j = row_ptr[i]; j < j1; j++) s += vf[srcs[j]];
        p0[i] = s;
    }
}

__global__ void k_p0_stats(const float* __restrict__ p0, float* __restrict__ stats, int n) {
    __shared__ float rs[256], rq[256];
    float s = 0.f, q = 0.f;
    for (int i = blockIdx.x * blockDim.x + threadIdx.x; i < n; i += gridDim.x * blockDim.x) {
        float v = p0[i]; s += v; q += v * v;
    }
    int t = threadIdx.x;
    rs[t] = s; rq[t] = q;
    __syncthreads();
    for (int o = 128; o > 0; o >>= 1) {
        if (t < o) { rs[t] += rs[t + o]; rq[t] += rq[t + o]; }
        __syncthreads();
    }
    if (t == 0) { unsafeAtomicAdd(&stats[0], rs[0]); unsafeAtomicAdd(&stats[1], rq[0]); }
}

__global__ void k_l0_prep(float* __restrict__ stats, const float* __restrict__ W1,
                          const float* __restrict__ g1, const float* __restrict__ bb1,
                          float* __restrict__ A0, float* __restrict__ Sh0, int n) {
    float mp = stats[0] / n;
    float vp = stats[1] / n - mp * mp;
    int c = threadIdx.x;
    float w = W1[c];
    A0[c] = w * rsqrtf(vp * w * w + 1e-5f) * g1[c];
    Sh0[c] = bb1[c];
    if (c == 0) stats[2] = mp;
}

// ---------------------------------------------------------------- BN+ReLU in place on f16 H
__global__ void k_prep_ip(f16* __restrict__ hz, const float* __restrict__ sc,
                          const float* __restrict__ sh, int n8) {
    for (int i = blockIdx.x * blockDim.x + threadIdx.x; i < n8; i += gridDim.x * blockDim.x) {
        int c0 = (i & 15) * 8;
        f16x8 v = *(const f16x8*)&hz[(size_t)i * 8];
        float4 s0 = *(const float4*)&sc[c0];
        float4 s1 = *(const float4*)&sc[c0 + 4];
        float4 h0 = *(const float4*)&sh[c0];
        float4 h1 = *(const float4*)&sh[c0 + 4];
        v[0] = (f16)fmaxf((float)v[0] * s0.x + h0.x, 0.f);
        v[1] = (f16)fmaxf((float)v[1] * s0.y + h0.y, 0.f);
        v[2] = (f16)fmaxf((float)v[2] * s0.z + h0.z, 0.f);
        v[3] = (f16)fmaxf((float)v[3] * s0.w + h0.w, 0.f);
        v[4] = (f16)fmaxf((float)v[4] * s1.x + h1.x, 0.f);
        v[5] = (f16)fmaxf((float)v[5] * s1.y + h1.y, 0.f);
        v[6] = (f16)fmaxf((float)v[6] * s1.z + h1.z, 0.f);
        v[7] = (f16)fmaxf((float)v[7] * s1.w + h1.w, 0.f);
        *(f16x8*)&hz[(size_t)i * 8] = v;
    }
}

static __device__ __forceinline__ void acc_sum(f16x8 v, float* a) {
#pragma unroll
    for (int j = 0; j < 8; j++) a[j] += (float)v[j];
}

// ---------------------------------------------------------------- pool + MFMA GEMM1 (measured-good R8 version)
__global__ __launch_bounds__(256) void k_pgemm(
    const f16* __restrict__ h, const int* __restrict__ row_ptr,
    const int* __restrict__ src_sorted, const float* __restrict__ eps, int li,
    const float* __restrict__ W, const float* __restrict__ bias,
    f16* __restrict__ out, float* __restrict__ gsum, float* __restrict__ gsq, int n) {
    __shared__ f16 Wl[HD * LDP];   // W^T [c][k], 34.8 KB
    __shared__ f16 Pl[32 * LDP];   // pooled tile [r][c], 8.7 KB
    const int t = threadIdx.x;
    const int lane = t & 63, w = t >> 6;
    const int l15 = lane & 15, lq = lane >> 4;

    for (int p = 0; p < 64; p++) {
        int idx = p * 256 + t;
        Wl[(idx & 127) * LDP + (idx >> 7)] = (f16)W[idx];
    }

    const int ga = t >> 4, ca = (t & 15) * 8;
    const float ep = 1.f + eps[li];

    const int rt = (w & 1) * 16;
    const int ctb = (w >> 1) * 4;
    float bv[4];
#pragma unroll
    for (int i = 0; i < 4; i++) bv[i] = bias[(ctb + i) * 16 + l15];

    float s8[8] = {0}, q8[8] = {0};
    const int ntiles = n / 32;
    for (int tile = blockIdx.x; tile < ntiles; tile += gridDim.x) {
        __syncthreads();
#pragma unroll
        for (int rr = 0; rr < 2; rr++) {
            const int r = tile * 32 + ga * 2 + rr;
            float a[8];
            {
                f16x8 u = *(const f16x8*)&h[(size_t)r * HD + ca];
#pragma unroll
                for (int j = 0; j < 8; j++) a[j] = ep * (float)u[j];
            }
            const int j0 = row_ptr[r], j1 = row_ptr[r + 1];
            int j = j0;
            for (; j + 3 < j1; j += 4) {
                int s0 = src_sorted[j], s1 = src_sorted[j + 1];
                int s2 = src_sorted[j + 2], s3 = src_sorted[j + 3];
                f16x8 v0 = *(const f16x8*)&h[(size_t)s0 * HD + ca];
                f16x8 v1 = *(const f16x8*)&h[(size_t)s1 * HD + ca];
                f16x8 v2 = *(const f16x8*)&h[(size_t)s2 * HD + ca];
                f16x8 v3 = *(const f16x8*)&h[(size_t)s3 * HD + ca];
                acc_sum(v0, a); acc_sum(v1, a); acc_sum(v2, a); acc_sum(v3, a);
            }
            for (; j < j1; j++) {
                f16x8 v = *(const f16x8*)&h[(size_t)src_sorted[j] * HD + ca];
                acc_sum(v, a);
            }
            f16x8 o;
#pragma unroll
            for (int jj = 0; jj < 8; jj++) o[jj] = (f16)a[jj];
            *(f16x8*)&Pl[(ga * 2 + rr) * LDP + ca] = o;
        }
        __syncthreads();
        f16x8 af[4];
#pragma unroll
        for (int k0 = 0; k0 < 4; k0++)
            af[k0] = *(const f16x8*)&Pl[(rt + l15) * LDP + k0 * 32 + 8 * lq];
        __syncthreads();
#pragma unroll
        for (int i = 0; i < 4; i++) {
            f32x4 acc = {0.f, 0.f, 0.f, 0.f};
            const int c0 = (ctb + i) * 16;
#pragma unroll
            for (int k0 = 0; k0 < 4; k0++) {
                f16x8 bf = *(const f16x8*)&Wl[(c0 + l15) * LDP + k0 * 32 + 8 * lq];
                acc = __builtin_amdgcn_mfma_f32_16x16x32_f16(af[k0], bf, acc, 0, 0, 0);
            }
#pragma unroll
            for (int ri = 0; ri < 4; ri++)
                Pl[(rt + lq * 4 + ri) * LDP + c0 + l15] = (f16)(acc[ri] + bv[i]);
        }
        __syncthreads();
#pragma unroll
        for (int p = 0; p < 2; p++) {
            int u = p * 256 + t;
            int row = u >> 4;
            f16x8 v = *(const f16x8*)&Pl[row * LDP + ca];
            *(f16x8*)&out[(size_t)(tile * 32 + row) * HD + ca] = v;
#pragma unroll
            for (int j = 0; j < 8; j++) {
                float f = (float)v[j];
                s8[j] += f; q8[j] += f * f;
            }
        }
    }

    __syncthreads();
    float* red = (float*)Wl;
#pragma unroll
    for (int j = 0; j < 8; j++) { red[t * 16 + j] = s8[j]; red[t * 16 + 8 + j] = q8[j]; }
    __syncthreads();
    if (t < HD) {
        int g = t >> 3, j = t & 7;
        float ts = 0.f, tq = 0.f;
#pragma unroll
        for (int i = 0; i < 16; i++) {
            ts += red[(i * 16 + g) * 16 + j];
            tq += red[(i * 16 + g) * 16 + 8 + j];
        }
        unsafeAtomicAdd(&gsum[t], ts);
        unsafeAtomicAdd(&gsq[t], tq);
    }
}

// ---------------------------------------------------------------- dense MFMA GEMM (n x 128)@(128 x 128)
template <int MODE>
__global__ __launch_bounds__(256) void k_gemm(
    const void* __restrict__ in_, const float* __restrict__ W,
    const float* __restrict__ bias,
    const float* __restrict__ tsc, const float* __restrict__ tsh,
    const float* __restrict__ mstat,
    f16* __restrict__ out, float* __restrict__ gsum, float* __restrict__ gsq, int n) {
    __shared__ f16 Wl[HD * LDP];   // 34.8 KB
    __shared__ f16 Al[64 * LDP];   // 17.4 KB
    const int t = threadIdx.x;
    const int lane = t & 63, w = t >> 6;
    const int l15 = lane & 15, lq = lane >> 4;

    for (int p = 0; p < 64; p++) {
        int idx = p * 256 + t;
        Wl[(idx & 127) * LDP + (idx >> 7)] = (f16)W[idx];
    }

    const int ca = (t & 15) * 8;
    float tscv[8], tshv[8];
    *(float4*)&tscv[0] = *(const float4*)&tsc[ca];
    *(float4*)&tscv[4] = *(const float4*)&tsc[ca + 4];
    *(float4*)&tshv[0] = *(const float4*)&tsh[ca];
    *(float4*)&tshv[4] = *(const float4*)&tsh[ca + 4];
    float mp = 0.f;
    if (MODE == 2) mp = mstat[2];
    float bv[8];
#pragma unroll
    for (int ct = 0; ct < 8; ct++) bv[ct] = bias[ct * 16 + l15];

    const int r0 = w * 16;
    float s8[8] = {0}, q8[8] = {0};
    const int ntiles = n / 64;
    for (int tile = blockIdx.x; tile < ntiles; tile += gridDim.x) {
        __syncthreads();
#pragma unroll
        for (int p = 0; p < 4; p++) {
            const int row = (t >> 4) + p * 16;
            const int grow = tile * 64 + row;
            f16x8 o;
            if (MODE == 1) {
                f16x8 zv = *(const f16x8*)&((const f16*)in_)[(size_t)grow * HD + ca];
#pragma unroll
                for (int j = 0; j < 8; j++)
                    o[j] = (f16)fmaxf((float)zv[j] * tscv[j] + tshv[j], 0.f);
            } else {
                const float pr = ((const float*)in_)[grow] - mp;
#pragma unroll
                for (int j = 0; j < 8; j++)
                    o[j] = (f16)fmaxf(pr * tscv[j] + tshv[j], 0.f);
            }
            *(f16x8*)&Al[row * LDP + ca] = o;
        }
        __syncthreads();
        f16x8 af[4];
#pragma unroll
        for (int k0 = 0; k0 < 4; k0++)
            af[k0] = *(const f16x8*)&Al[(r0 + l15) * LDP + k0 * 32 + 8 * lq];
#pragma unroll
        for (int ct = 0; ct < 8; ct++) {
            f32x4 acc = {0.f, 0.f, 0.f, 0.f};
#pragma unroll
            for (int k0 = 0; k0 < 4; k0++) {
                f16x8 bf = *(const f16x8*)&Wl[(ct * 16 + l15) * LDP + k0 * 32 + 8 * lq];
                acc = __builtin_amdgcn_mfma_f32_16x16x32_f16(af[k0], bf, acc, 0, 0, 0);
            }
#pragma unroll
            for (int ri = 0; ri < 4; ri++)
                Al[(r0 + lq * 4 + ri) * LDP + ct * 16 + l15] = (f16)(acc[ri] + bv[ct]);
        }
        __syncthreads();
#pragma unroll
        for (int p = 0; p < 4; p++) {
            int row = (t >> 4) + p * 16;
            f16x8 v = *(const f16x8*)&Al[row * LDP + ca];
            *(f16x8*)&out[(size_t)(tile * 64 + row) * HD + ca] = v;
#pragma unroll
            for (int j = 0; j < 8; j++) {
                float f = (float)v[j];
                s8[j] += f; q8[j] += f * f;
            }
        }
    }

    __syncthreads();
    float* red = (float*)Al;
#pragma unroll
    for (int j = 0; j < 8; j++) { red[t * 16 + j] = s8[j]; red[t * 16 + 8 + j] = q8[j]; }
    __syncthreads();
    if (t < HD) {
        int g = t >> 3, j = t & 7;
        float ts = 0.f, tq = 0.f;
#pragma unroll
        for (int i = 0; i < 16; i++) {
            ts += red[(i * 16 + g) * 16 + j];
            tq += red[(i * 16 + g) * 16 + 8 + j];
        }
        unsafeAtomicAdd(&gsum[t], ts);
        unsafeAtomicAdd(&gsq[t], tq);
    }
}

// mean/var -> affine (sc, sh)
__global__ void k_finalize(const float* __restrict__ gsum, const float* __restrict__ gsq,
                           const float* __restrict__ g, const float* __restrict__ b,
                           float* __restrict__ sc, float* __restrict__ sh, int n) {
    int c = threadIdx.x;
    float m = gsum[c] / n;
    float v = gsq[c] / n - m * m;
    float s = rsqrtf(v + 1e-5f) * g[c];
    sc[c] = s;
    sh[c] = b[c] - m * s;
}

// classifier head (applies final BN affine itself), reads f16 z
__global__ void k_head(const unsigned short* __restrict__ z, const float* __restrict__ sc,
                       const float* __restrict__ sh, const float* __restrict__ fw,
                       const float* __restrict__ fb, float* __restrict__ out, int n) {
    int gid  = blockIdx.x * blockDim.x + threadIdx.x;
    int lane = threadIdx.x & 63;
    int w    = gid >> 6;
    int nw   = (gridDim.x * blockDim.x) >> 6;
    int c    = lane * 2;
    float s0 = sc[c], s1 = sc[c + 1], t0 = sh[c], t1 = sh[c + 1];
    float w00 = fw[c * 2], w01 = fw[c * 2 + 1], w10 = fw[c * 2 + 2], w11 = fw[c * 2 + 3];
    float fb0 = fb[0], fb1 = fb[1];
    for (int r = w; r < n; r += nw) {
        unsigned int u = *(const unsigned int*)&z[(size_t)r * HD + c];
        float zx = h2f((unsigned short)(u & 0xffffu));
        float zy = h2f((unsigned short)(u >> 16));
        float x0 = fmaxf(zx * s0 + t0, 0.f);
        float x1 = fmaxf(zy * s1 + t1, 0.f);
        float l0 = x0 * w00 + x1 * w10;
        float l1 = x0 * w01 + x1 * w11;
#pragma unroll
        for (int o = 32; o > 0; o >>= 1) {
            l0 += __shfl_xor(l0, o, 64);
            l1 += __shfl_xor(l1, o, 64);
        }
        if (lane == 0) {
            l0 += fb0; l1 += fb1;
            float m  = fmaxf(l0, l1);
            float e0 = expf(l0 - m), e1 = expf(l1 - m);
            float inv = 1.f / (e0 + e1);
            *(float2*)&out[(size_t)r * 2] = make_float2(e0 * inv, e1 * inv);
        }
    }
}

extern "C" void kernel_launch(void* const* d_in, const int* in_sizes, int n_in,
                              void* d_out, int out_size, void* d_ws, size_t ws_size,
                              hipStream_t stream) {
    const float* vf    = (const float*)d_in[1];
    const int*   src   = (const int*)d_in[2];
    const int*   dst   = (const int*)d_in[3];
    const float* eps   = (const float*)d_in[4];
    const float* W1_0  = (const float*)d_in[5];
    const float* g1_0  = (const float*)d_in[7];
    const float* bb1_0 = (const float*)d_in[8];
    const float* W2_0  = (const float*)d_in[9];
    const float* b2_0  = (const float*)d_in[10];
    const float* bn0g  = (const float*)d_in[11];
    const float* bn0b  = (const float*)d_in[12];
    const float* W1s   = (const float*)d_in[13];
    const float* b1s   = (const float*)d_in[14];
    const float* g1s   = (const float*)d_in[15];
    const float* bb1s  = (const float*)d_in[16];
    const float* W2s   = (const float*)d_in[17];
    const float* b2s   = (const float*)d_in[18];
    const float* bngs  = (const float*)d_in[19];
    const float* bnbs  = (const float*)d_in[20];
    const float* fw    = (const float*)d_in[21];
    const float* fb    = (const float*)d_in[22];
    float* out = (float*)d_out;

    const int N = in_sizes[1];  // 400000
    const int E = in_sizes[2];  // 6400000
    const int NBUK = (N + CMSK) >> CSH;          // coarse buckets (98)
    const int NCH  = (E + CHSZ - 1) >> CHSH;     // partition chunks (782)
    const int NFLAT = NBUK * NCH;                // 76636

    const size_t needed = (size_t)N * HD * 2 * 2 + (size_t)(N + 8 + 9 * 128 + 512) * 4
                        + (size_t)(N + 1 + E) * 4 + (size_t)(NFLAT + 2) * 4;
    if (ws_size < needed || NBUK > 128) {
        float code = (float)(double)(ws_size >> 20);
        k_diag<<<2048, 256, 0, stream>>>(out, out_size, code);
        return;
    }

    f16* H            = (f16*)d_ws;                 // z2 raw -> activated in place
    f16* Z            = H + (size_t)N * HD;         // z1 raw (also aliased as CSR temp)
    float* p0         = (float*)(Z + (size_t)N * HD);
    float* stats      = p0 + N;
    float* gsum       = stats + 8;
    float* gsq        = gsum + HD;
    float* sc1        = gsq + HD;
    float* sh1        = sc1 + HD;
    float* sc2        = sh1 + HD;
    float* sh2        = sc2 + HD;
    float* A0         = sh2 + HD;
    float* Sh0        = A0 + HD;
    int* bsum         = (int*)(Sh0 + HD);  // 512
    int* row_ptr      = bsum + 512;        // N+1
    int* src_sorted   = row_ptr + (N + 1); // E
    int* ccnt         = src_sorted + E;    // NFLAT+1
    int* tmp          = (int*)Z;           // E (aliases Z; free until layer 1)

    // -------- CSR build: chunk-owned counting sort -> per-bucket fine build
    const int n2 = NFLAT + 1;
    const int nsb2 = (n2 + SCAN_B - 1) / SCAN_B;
    k_zeroi<<<(n2 + 65535) / 65536, 256, 0, stream>>>(ccnt, n2);
    k_cnt<<<NCH, 256, 0, stream>>>(dst, ccnt, E, NCH, NBUK);
    k_scan_block<<<nsb2, SCAN_B, 0, stream>>>(ccnt, n2, bsum);
    k_scan_serial<<<1, 1, 0, stream>>>(bsum, nsb2);
    k_scan_add<<<nsb2, SCAN_B, 0, stream>>>(ccnt, n2, bsum);
    k_part2<<<NCH, 256, 0, stream>>>(src, dst, ccnt, tmp, E, NCH, NBUK);
    k_build<<<NBUK, 1024, 0, stream>>>(tmp, ccnt, row_ptr, src_sorted, N, E, NBUK, NCH);

    // -------- layer 0 (scalar features, rank-1 inner BN shortcut)
    k_pool0<<<2048, 256, 0, stream>>>(vf, row_ptr, src_sorted, eps, p0, N);
    k_zero<<<1, 256, 0, stream>>>(stats, 8);
    k_p0_stats<<<1024, 256, 0, stream>>>(p0, stats, N);
    k_l0_prep<<<1, 128, 0, stream>>>(stats, W1_0, g1_0, bb1_0, A0, Sh0, N);
    k_zero<<<1, 256, 0, stream>>>(gsum, 2 * HD);
    k_gemm<2><<<2048, 256, 0, stream>>>(p0, W2_0, b2_0, A0, Sh0, stats, H, gsum, gsq, N);
    k_finalize<<<1, 128, 0, stream>>>(gsum, gsq, bn0g, bn0b, sc2, sh2, N);

    // -------- layers 1..3
    for (int l = 0; l < 3; l++) {
        k_prep_ip<<<4096, 256, 0, stream>>>(H, sc2, sh2, N * (HD / 8));
        k_zero<<<1, 256, 0, stream>>>(gsum, 2 * HD);
        k_pgemm<<<2048, 256, 0, stream>>>(H, row_ptr, src_sorted, eps, l + 1,
                                          W1s + (size_t)l * HD * HD, b1s + l * HD,
                                          Z, gsum, gsq, N);
        k_finalize<<<1, 128, 0, stream>>>(gsum, gsq, g1s + l * HD, bb1s + l * HD, sc1, sh1, N);
        k_zero<<<1, 256, 0, stream>>>(gsum, 2 * HD);
        k_gemm<1><<<2048, 256, 0, stream>>>(Z, W2s + (size_t)l * HD * HD, b2s + l * HD,
                                            sc1, sh1, nullptr, H, gsum, gsq, N);
        k_finalize<<<1, 128, 0, stream>>>(gsum, gsq, bngs + l * HD, bnbs + l * HD, sc2, sh2, N);
    }

    // -------- classifier head + softmax
    k_head<<<4096, 256, 0, stream>>>((const unsigned short*)H, sc2, sh2, fw, fb, out, N);
}

// Round 12
// 1730.935 us; speedup vs baseline: 2.0782x; 1.0415x over previous
//
#include <hip/hip_runtime.h>
#include <math.h>

#define HD 128
#define LDP 136   // padded LDS row stride in f16 elems
#define CSH 12    // coarse bucket shift (4096 dst per bucket)
#define CMSK 4095
#define CHSH 13   // 8192 edges per partition chunk
#define CHSZ 8192

typedef _Float16 f16;
typedef _Float16 f16x8 __attribute__((ext_vector_type(8)));
typedef float f32x4 __attribute__((ext_vector_type(4)));
typedef unsigned int u32x4 __attribute__((ext_vector_type(4)));

static __device__ __forceinline__ float h2f(unsigned short s) {
    f16 v; __builtin_memcpy(&v, &s, 2); return (float)v;
}

// ---------------------------------------------------------------- diagnostic
__global__ void k_diag(float* __restrict__ out, int n, float val) {
    for (int i = blockIdx.x * blockDim.x + threadIdx.x; i < n; i += gridDim.x * blockDim.x)
        out[i] = val;
}

// ---------------------------------------------------------------- utility
__global__ void k_zero(float* __restrict__ p, int n) {
    for (int i = threadIdx.x; i < n; i += blockDim.x) p[i] = 0.f;
}
__global__ void k_zeroi(int* __restrict__ p, int n) {
    for (int i = blockIdx.x * blockDim.x + threadIdx.x; i < n; i += gridDim.x * blockDim.x)
        p[i] = 0;
}

// ---------------------------------------------------------------- CSR build (chunk-owned counting sort)
__global__ __launch_bounds__(256) void k_cnt(const int* __restrict__ dst,
                                             int* __restrict__ ccnt,
                                             int e, int nchunks, int nbuk) {
    __shared__ int lh[128];
    const int c = blockIdx.x;
    const int base = c << CHSH;
    const int hi = min(base + CHSZ, e);
    for (int i = threadIdx.x; i < 128; i += 256) lh[i] = 0;
    __syncthreads();
    for (int i = base + threadIdx.x; i < hi; i += 256)
        atomicAdd(&lh[dst[i] >> CSH], 1);
    __syncthreads();
    for (int b = threadIdx.x; b < 128; b += 256)
        if (b < nbuk && lh[b]) ccnt[(b * nchunks + c) + 1] = lh[b];
}

#define SCAN_B 1024
__global__ void k_scan_block(int* __restrict__ a, int n, int* __restrict__ bsum) {
    __shared__ int s[SCAN_B];
    int base = blockIdx.x * SCAN_B;
    int i = base + threadIdx.x;
    int v = (i < n) ? a[i] : 0;
    s[threadIdx.x] = v;
    __syncthreads();
    for (int o = 1; o < SCAN_B; o <<= 1) {
        int t = (threadIdx.x >= o) ? s[threadIdx.x - o] : 0;
        __syncthreads();
        s[threadIdx.x] += t;
        __syncthreads();
    }
    if (i < n) a[i] = s[threadIdx.x];
    if (threadIdx.x == 0) bsum[blockIdx.x] = s[SCAN_B - 1];
}
__global__ void k_scan_serial(int* __restrict__ bsum, int nb) {
    int run = 0;
    for (int b = 0; b < nb; b++) { int t = bsum[b]; bsum[b] = run; run += t; }
}
__global__ void k_scan_add(int* __restrict__ a, int n, const int* __restrict__ bsum) {
    int base = blockIdx.x * SCAN_B;
    int i = base + threadIdx.x;
    if (i < n) a[i] += bsum[blockIdx.x];
}

__global__ __launch_bounds__(256) void k_part2(const int* __restrict__ src,
                                               const int* __restrict__ dst,
                                               const int* __restrict__ ccnt,
                                               int* __restrict__ tmp,
                                               int e, int nchunks, int nbuk) {
    __shared__ int lh[128];
    const int c = blockIdx.x;
    const int base = c << CHSH;
    const int hi = min(base + CHSZ, e);
    for (int b = threadIdx.x; b < 128; b += 256)
        lh[b] = (b < nbuk) ? ccnt[b * nchunks + c] : 0;
    __syncthreads();
    for (int i = base + threadIdx.x; i < hi; i += 256) {
        int d = dst[i];
        int pos = atomicAdd(&lh[d >> CSH], 1);
        tmp[pos] = (src[i] << CSH) | (d & CMSK);
    }
}

__global__ __launch_bounds__(1024) void k_build(const int* __restrict__ tmp,
                                                const int* __restrict__ ccnt,
                                                int* __restrict__ row_ptr,
                                                int* __restrict__ src_sorted,
                                                int n, int e, int nb, int stride) {
    __shared__ int lh[4096];
    __shared__ int part[1024];
    const int b = blockIdx.x;
    const int t = threadIdx.x;
    const int lo = ccnt[b * stride], hi = ccnt[(b + 1) * stride];
    for (int i = t; i < 4096; i += 1024) lh[i] = 0;
    __syncthreads();
    for (int i = lo + t; i < hi; i += 1024)
        atomicAdd(&lh[tmp[i] & CMSK], 1);
    __syncthreads();
    const int base4 = t * 4;
    int a0 = lh[base4], a1 = lh[base4 + 1], a2 = lh[base4 + 2], a3 = lh[base4 + 3];
    int tsum = a0 + a1 + a2 + a3;
    part[t] = tsum;
    __syncthreads();
    for (int o = 1; o < 1024; o <<= 1) {
        int tv = (t >= o) ? part[t - o] : 0;
        __syncthreads();
        part[t] += tv;
        __syncthreads();
    }
    int off = part[t] - tsum;
    lh[base4] = off;
    lh[base4 + 1] = off + a0;
    lh[base4 + 2] = off + a0 + a1;
    lh[base4 + 3] = off + a0 + a1 + a2;
    __syncthreads();
    for (int d0 = t; d0 < 4096; d0 += 1024) {
        int gd = (b << CSH) + d0;
        if (gd < n) row_ptr[gd] = lo + lh[d0];
    }
    if (b == nb - 1 && t == 0) row_ptr[n] = e;
    __syncthreads();
    for (int i = lo + t; i < hi; i += 1024) {
        int e2 = tmp[i];
        int pos = lo + atomicAdd(&lh[e2 & CMSK], 1);
        src_sorted[pos] = ((unsigned int)e2) >> CSH;
    }
}

// ---------------------------------------------------------------- layer 0
__global__ void k_pool0(const float* __restrict__ vf, const int* __restrict__ row_ptr,
                        const int* __restrict__ srcs, const float* __restrict__ eps,
                        float* __restrict__ p0, int n) {
    float ep = 1.f + eps[0];
    for (int i = blockIdx.x * blockDim.x + threadIdx.x; i < n; i += gridDim.x * blockDim.x) {
        float s = ep * vf[i];
        int j1 = row_ptr[i + 1];
        for (int j = row_ptr[i]; j < j1; j++) s += vf[srcs[j]];
        p0[i] = s;
    }
}

__global__ void k_p0_stats(const float* __restrict__ p0, float* __restrict__ stats, int n) {
    __shared__ float rs[256], rq[256];
    float s = 0.f, q = 0.f;
    for (int i = blockIdx.x * blockDim.x + threadIdx.x; i < n; i += gridDim.x * blockDim.x) {
        float v = p0[i]; s += v; q += v * v;
    }
    int t = threadIdx.x;
    rs[t] = s; rq[t] = q;
    __syncthreads();
    for (int o = 128; o > 0; o >>= 1) {
        if (t < o) { rs[t] += rs[t + o]; rq[t] += rq[t + o]; }
        __syncthreads();
    }
    if (t == 0) { unsafeAtomicAdd(&stats[0], rs[0]); unsafeAtomicAdd(&stats[1], rq[0]); }
}

__global__ void k_l0_prep(float* __restrict__ stats, const float* __restrict__ W1,
                          const float* __restrict__ g1, const float* __restrict__ bb1,
                          float* __restrict__ A0, float* __restrict__ Sh0, int n) {
    float mp = stats[0] / n;
    float vp = stats[1] / n - mp * mp;
    int c = threadIdx.x;
    float w = W1[c];
    A0[c] = w * rsqrtf(vp * w * w + 1e-5f) * g1[c];
    Sh0[c] = bb1[c];
    if (c == 0) stats[2] = mp;
}

// ---------------------------------------------------------------- BN+ReLU in place on f16 H
__global__ void k_prep_ip(f16* __restrict__ hz, const float* __restrict__ sc,
                          const float* __restrict__ sh, int n8) {
    for (int i = blockIdx.x * blockDim.x + threadIdx.x; i < n8; i += gridDim.x * blockDim.x) {
        int c0 = (i & 15) * 8;
        f16x8 v = *(const f16x8*)&hz[(size_t)i * 8];
        float4 s0 = *(const float4*)&sc[c0];
        float4 s1 = *(const float4*)&sc[c0 + 4];
        float4 h0 = *(const float4*)&sh[c0];
        float4 h1 = *(const float4*)&sh[c0 + 4];
        v[0] = (f16)fmaxf((float)v[0] * s0.x + h0.x, 0.f);
        v[1] = (f16)fmaxf((float)v[1] * s0.y + h0.y, 0.f);
        v[2] = (f16)fmaxf((float)v[2] * s0.z + h0.z, 0.f);
        v[3] = (f16)fmaxf((float)v[3] * s0.w + h0.w, 0.f);
        v[4] = (f16)fmaxf((float)v[4] * s1.x + h1.x, 0.f);
        v[5] = (f16)fmaxf((float)v[5] * s1.y + h1.y, 0.f);
        v[6] = (f16)fmaxf((float)v[6] * s1.z + h1.z, 0.f);
        v[7] = (f16)fmaxf((float)v[7] * s1.w + h1.w, 0.f);
        *(f16x8*)&hz[(size_t)i * 8] = v;
    }
}

static __device__ __forceinline__ void acc_sum(f16x8 v, float* a) {
#pragma unroll
    for (int j = 0; j < 8; j++) a[j] += (float)v[j];
}

// ---------------------------------------------------------------- pool + MFMA GEMM1
// 512 threads / 64-row tiles: the 34.8 KB W^T LDS tile is shared by 8 waves,
// so 3 blocks/CU = 24 waves/CU potential (VGPR caps at 16) vs 12 before.
// Inner per-thread code identical to the measured-good R8/R11 version.
// Z written non-temporally (read once downstream; keep H hot in L2/L3).
__global__ __launch_bounds__(512) void k_pgemm(
    const f16* __restrict__ h, const int* __restrict__ row_ptr,
    const int* __restrict__ src_sorted, const float* __restrict__ eps, int li,
    const float* __restrict__ W, const float* __restrict__ bias,
    f16* __restrict__ out, float* __restrict__ gsum, float* __restrict__ gsq, int n) {
    __shared__ f16 Wl[HD * LDP];   // W^T [c][k], 34.8 KB
    __shared__ f16 Pl[64 * LDP];   // pooled tile [r][c], 17.4 KB
    const int t = threadIdx.x;
    const int lane = t & 63, w = t >> 6;          // 8 waves
    const int l15 = lane & 15, lq = lane >> 4;

    for (int p = 0; p < 32; p++) {
        int idx = p * 512 + t;
        Wl[(idx & 127) * LDP + (idx >> 7)] = (f16)W[idx];
    }

    const int ga = t >> 4, ca = (t & 15) * 8;     // 32 gather groups
    const float ep = 1.f + eps[li];

    const int rt = (w & 3) * 16;                  // 4 row-tiles
    const int ctb = (w >> 2) * 4;                 // 2 x 4 col-tiles
    float bv[4];
#pragma unroll
    for (int i = 0; i < 4; i++) bv[i] = bias[(ctb + i) * 16 + l15];

    float s8[8] = {0}, q8[8] = {0};
    const int ntiles = n / 64;
    for (int tile = blockIdx.x; tile < ntiles; tile += gridDim.x) {
        __syncthreads();
        // ---- Phase A: 2 rows per 16-lane group, pure sum gather
#pragma unroll
        for (int rr = 0; rr < 2; rr++) {
            const int r = tile * 64 + ga * 2 + rr;
            float a[8];
            {
                f16x8 u = *(const f16x8*)&h[(size_t)r * HD + ca];
#pragma unroll
                for (int j = 0; j < 8; j++) a[j] = ep * (float)u[j];
            }
            const int j0 = row_ptr[r], j1 = row_ptr[r + 1];
            int j = j0;
            for (; j + 3 < j1; j += 4) {
                int s0 = src_sorted[j], s1 = src_sorted[j + 1];
                int s2 = src_sorted[j + 2], s3 = src_sorted[j + 3];
                f16x8 v0 = *(const f16x8*)&h[(size_t)s0 * HD + ca];
                f16x8 v1 = *(const f16x8*)&h[(size_t)s1 * HD + ca];
                f16x8 v2 = *(const f16x8*)&h[(size_t)s2 * HD + ca];
                f16x8 v3 = *(const f16x8*)&h[(size_t)s3 * HD + ca];
                acc_sum(v0, a); acc_sum(v1, a); acc_sum(v2, a); acc_sum(v3, a);
            }
            for (; j < j1; j++) {
                f16x8 v = *(const f16x8*)&h[(size_t)src_sorted[j] * HD + ca];
                acc_sum(v, a);
            }
            f16x8 o;
#pragma unroll
            for (int jj = 0; jj < 8; jj++) o[jj] = (f16)a[jj];
            *(f16x8*)&Pl[(ga * 2 + rr) * LDP + ca] = o;
        }
        __syncthreads();
        // ---- hoist A fragments (rows rt..rt+15)
        f16x8 af[4];
#pragma unroll
        for (int k0 = 0; k0 < 4; k0++)
            af[k0] = *(const f16x8*)&Pl[(rt + l15) * LDP + k0 * 32 + 8 * lq];
        __syncthreads();
        // ---- MFMA (4 col-tiles) + writeback to Pl (f16, bias added)
#pragma unroll
        for (int i = 0; i < 4; i++) {
            f32x4 acc = {0.f, 0.f, 0.f, 0.f};
            const int c0 = (ctb + i) * 16;
#pragma unroll
            for (int k0 = 0; k0 < 4; k0++) {
                f16x8 bf = *(const f16x8*)&Wl[(c0 + l15) * LDP + k0 * 32 + 8 * lq];
                acc = __builtin_amdgcn_mfma_f32_16x16x32_f16(af[k0], bf, acc, 0, 0, 0);
            }
#pragma unroll
            for (int ri = 0; ri < 4; ri++)
                Pl[(rt + lq * 4 + ri) * LDP + c0 + l15] = (f16)(acc[ri] + bv[i]);
        }
        __syncthreads();
        // ---- epilogue: 2 f16x8 per thread, nt store + stats
#pragma unroll
        for (int p = 0; p < 2; p++) {
            const int row = (p * 512 + t) >> 4;
            f16x8 v = *(const f16x8*)&Pl[row * LDP + ca];
            u32x4 v4 = *(u32x4*)&v;
            __builtin_nontemporal_store(v4, (u32x4*)&out[(size_t)(tile * 64 + row) * HD + ca]);
#pragma unroll
            for (int j = 0; j < 8; j++) {
                float f = (float)v[j];
                s8[j] += f; q8[j] += f * f;
            }
        }
    }

    // ---- stats block reduction (reuse Wl as f32 scratch: 512*16*4 = 32 KB)
    __syncthreads();
    float* red = (float*)Wl;
#pragma unroll
    for (int j = 0; j < 8; j++) { red[t * 16 + j] = s8[j]; red[t * 16 + 8 + j] = q8[j]; }
    __syncthreads();
    if (t < HD) {
        int g = t >> 3, j = t & 7;
        float ts = 0.f, tq = 0.f;
#pragma unroll
        for (int i = 0; i < 32; i++) {
            ts += red[(i * 16 + g) * 16 + j];
            tq += red[(i * 16 + g) * 16 + 8 + j];
        }
        unsafeAtomicAdd(&gsum[t], ts);
        unsafeAtomicAdd(&gsq[t], tq);
    }
}

// ---------------------------------------------------------------- dense MFMA GEMM (n x 128)@(128 x 128)
template <int MODE>
__global__ __launch_bounds__(256) void k_gemm(
    const void* __restrict__ in_, const float* __restrict__ W,
    const float* __restrict__ bias,
    const float* __restrict__ tsc, const float* __restrict__ tsh,
    const float* __restrict__ mstat,
    f16* __restrict__ out, float* __restrict__ gsum, float* __restrict__ gsq, int n) {
    __shared__ f16 Wl[HD * LDP];   // 34.8 KB
    __shared__ f16 Al[64 * LDP];   // 17.4 KB
    const int t = threadIdx.x;
    const int lane = t & 63, w = t >> 6;
    const int l15 = lane & 15, lq = lane >> 4;

    for (int p = 0; p < 64; p++) {
        int idx = p * 256 + t;
        Wl[(idx & 127) * LDP + (idx >> 7)] = (f16)W[idx];
    }

    const int ca = (t & 15) * 8;
    float tscv[8], tshv[8];
    *(float4*)&tscv[0] = *(const float4*)&tsc[ca];
    *(float4*)&tscv[4] = *(const float4*)&tsc[ca + 4];
    *(float4*)&tshv[0] = *(const float4*)&tsh[ca];
    *(float4*)&tshv[4] = *(const float4*)&tsh[ca + 4];
    float mp = 0.f;
    if (MODE == 2) mp = mstat[2];
    float bv[8];
#pragma unroll
    for (int ct = 0; ct < 8; ct++) bv[ct] = bias[ct * 16 + l15];

    const int r0 = w * 16;
    float s8[8] = {0}, q8[8] = {0};
    const int ntiles = n / 64;
    for (int tile = blockIdx.x; tile < ntiles; tile += gridDim.x) {
        __syncthreads();
#pragma unroll
        for (int p = 0; p < 4; p++) {
            const int row = (t >> 4) + p * 16;
            const int grow = tile * 64 + row;
            f16x8 o;
            if (MODE == 1) {
                f16x8 zv = *(const f16x8*)&((const f16*)in_)[(size_t)grow * HD + ca];
#pragma unroll
                for (int j = 0; j < 8; j++)
                    o[j] = (f16)fmaxf((float)zv[j] * tscv[j] + tshv[j], 0.f);
            } else {
                const float pr = ((const float*)in_)[grow] - mp;
#pragma unroll
                for (int j = 0; j < 8; j++)
                    o[j] = (f16)fmaxf(pr * tscv[j] + tshv[j], 0.f);
            }
            *(f16x8*)&Al[row * LDP + ca] = o;
        }
        __syncthreads();
        f16x8 af[4];
#pragma unroll
        for (int k0 = 0; k0 < 4; k0++)
            af[k0] = *(const f16x8*)&Al[(r0 + l15) * LDP + k0 * 32 + 8 * lq];
#pragma unroll
        for (int ct = 0; ct < 8; ct++) {
            f32x4 acc = {0.f, 0.f, 0.f, 0.f};
#pragma unroll
            for (int k0 = 0; k0 < 4; k0++) {
                f16x8 bf = *(const f16x8*)&Wl[(ct * 16 + l15) * LDP + k0 * 32 + 8 * lq];
                acc = __builtin_amdgcn_mfma_f32_16x16x32_f16(af[k0], bf, acc, 0, 0, 0);
            }
#pragma unroll
            for (int ri = 0; ri < 4; ri++)
                Al[(r0 + lq * 4 + ri) * LDP + ct * 16 + l15] = (f16)(acc[ri] + bv[ct]);
        }
        __syncthreads();
#pragma unroll
        for (int p = 0; p < 4; p++) {
            int row = (t >> 4) + p * 16;
            f16x8 v = *(const f16x8*)&Al[row * LDP + ca];
            *(f16x8*)&out[(size_t)(tile * 64 + row) * HD + ca] = v;
#pragma unroll
            for (int j = 0; j < 8; j++) {
                float f = (float)v[j];
                s8[j] += f; q8[j] += f * f;
            }
        }
    }

    __syncthreads();
    float* red = (float*)Al;
#pragma unroll
    for (int j = 0; j < 8; j++) { red[t * 16 + j] = s8[j]; red[t * 16 + 8 + j] = q8[j]; }
    __syncthreads();
    if (t < HD) {
        int g = t >> 3, j = t & 7;
        float ts = 0.f, tq = 0.f;
#pragma unroll
        for (int i = 0; i < 16; i++) {
            ts += red[(i * 16 + g) * 16 + j];
            tq += red[(i * 16 + g) * 16 + 8 + j];
        }
        unsafeAtomicAdd(&gsum[t], ts);
        unsafeAtomicAdd(&gsq[t], tq);
    }
}

// mean/var -> affine (sc, sh)
__global__ void k_finalize(const float* __restrict__ gsum, const float* __restrict__ gsq,
                           const float* __restrict__ g, const float* __restrict__ b,
                           float* __restrict__ sc, float* __restrict__ sh, int n) {
    int c = threadIdx.x;
    float m = gsum[c] / n;
    float v = gsq[c] / n - m * m;
    float s = rsqrtf(v + 1e-5f) * g[c];
    sc[c] = s;
    sh[c] = b[c] - m * s;
}

// classifier head (applies final BN affine itself), reads f16 z
__global__ void k_head(const unsigned short* __restrict__ z, const float* __restrict__ sc,
                       const float* __restrict__ sh, const float* __restrict__ fw,
                       const float* __restrict__ fb, float* __restrict__ out, int n) {
    int gid  = blockIdx.x * blockDim.x + threadIdx.x;
    int lane = threadIdx.x & 63;
    int w    = gid >> 6;
    int nw   = (gridDim.x * blockDim.x) >> 6;
    int c    = lane * 2;
    float s0 = sc[c], s1 = sc[c + 1], t0 = sh[c], t1 = sh[c + 1];
    float w00 = fw[c * 2], w01 = fw[c * 2 + 1], w10 = fw[c * 2 + 2], w11 = fw[c * 2 + 3];
    float fb0 = fb[0], fb1 = fb[1];
    for (int r = w; r < n; r += nw) {
        unsigned int u = *(const unsigned int*)&z[(size_t)r * HD + c];
        float zx = h2f((unsigned short)(u & 0xffffu));
        float zy = h2f((unsigned short)(u >> 16));
        float x0 = fmaxf(zx * s0 + t0, 0.f);
        float x1 = fmaxf(zy * s1 + t1, 0.f);
        float l0 = x0 * w00 + x1 * w10;
        float l1 = x0 * w01 + x1 * w11;
#pragma unroll
        for (int o = 32; o > 0; o >>= 1) {
            l0 += __shfl_xor(l0, o, 64);
            l1 += __shfl_xor(l1, o, 64);
        }
        if (lane == 0) {
            l0 += fb0; l1 += fb1;
            float m  = fmaxf(l0, l1);
            float e0 = expf(l0 - m), e1 = expf(l1 - m);
            float inv = 1.f / (e0 + e1);
            *(float2*)&out[(size_t)r * 2] = make_float2(e0 * inv, e1 * inv);
        }
    }
}

extern "C" void kernel_launch(void* const* d_in, const int* in_sizes, int n_in,
                              void* d_out, int out_size, void* d_ws, size_t ws_size,
                              hipStream_t stream) {
    const float* vf    = (const float*)d_in[1];
    const int*   src   = (const int*)d_in[2];
    const int*   dst   = (const int*)d_in[3];
    const float* eps   = (const float*)d_in[4];
    const float* W1_0  = (const float*)d_in[5];
    const float* g1_0  = (const float*)d_in[7];
    const float* bb1_0 = (const float*)d_in[8];
    const float* W2_0  = (const float*)d_in[9];
    const float* b2_0  = (const float*)d_in[10];
    const float* bn0g  = (const float*)d_in[11];
    const float* bn0b  = (const float*)d_in[12];
    const float* W1s   = (const float*)d_in[13];
    const float* b1s   = (const float*)d_in[14];
    const float* g1s   = (const float*)d_in[15];
    const float* bb1s  = (const float*)d_in[16];
    const float* W2s   = (const float*)d_in[17];
    const float* b2s   = (const float*)d_in[18];
    const float* bngs  = (const float*)d_in[19];
    const float* bnbs  = (const float*)d_in[20];
    const float* fw    = (const float*)d_in[21];
    const float* fb    = (const float*)d_in[22];
    float* out = (float*)d_out;

    const int N = in_sizes[1];  // 400000
    const int E = in_sizes[2];  // 6400000
    const int NBUK = (N + CMSK) >> CSH;          // coarse buckets (98)
    const int NCH  = (E + CHSZ - 1) >> CHSH;     // partition chunks (782)
    const int NFLAT = NBUK * NCH;                // 76636

    const size_t needed = (size_t)N * HD * 2 * 2 + (size_t)(N + 8 + 9 * 128 + 512) * 4
                        + (size_t)(N + 1 + E) * 4 + (size_t)(NFLAT + 2) * 4;
    if (ws_size < needed || NBUK > 128) {
        float code = (float)(double)(ws_size >> 20);
        k_diag<<<2048, 256, 0, stream>>>(out, out_size, code);
        return;
    }

    f16* H            = (f16*)d_ws;                 // z2 raw -> activated in place
    f16* Z            = H + (size_t)N * HD;         // z1 raw (also aliased as CSR temp)
    float* p0         = (float*)(Z + (size_t)N * HD);
    float* stats      = p0 + N;
    float* gsum       = stats + 8;
    float* gsq        = gsum + HD;
    float* sc1        = gsq + HD;
    float* sh1        = sc1 + HD;
    float* sc2        = sh1 + HD;
    float* sh2        = sc2 + HD;
    float* A0         = sh2 + HD;
    float* Sh0        = A0 + HD;
    int* bsum         = (int*)(Sh0 + HD);  // 512
    int* row_ptr      = bsum + 512;        // N+1
    int* src_sorted   = row_ptr + (N + 1); // E
    int* ccnt         = src_sorted + E;    // NFLAT+1
    int* tmp          = (int*)Z;           // E (aliases Z; free until layer 1)

    // -------- CSR build: chunk-owned counting sort -> per-bucket fine build
    const int n2 = NFLAT + 1;
    const int nsb2 = (n2 + SCAN_B - 1) / SCAN_B;
    k_zeroi<<<(n2 + 65535) / 65536, 256, 0, stream>>>(ccnt, n2);
    k_cnt<<<NCH, 256, 0, stream>>>(dst, ccnt, E, NCH, NBUK);
    k_scan_block<<<nsb2, SCAN_B, 0, stream>>>(ccnt, n2, bsum);
    k_scan_serial<<<1, 1, 0, stream>>>(bsum, nsb2);
    k_scan_add<<<nsb2, SCAN_B, 0, stream>>>(ccnt, n2, bsum);
    k_part2<<<NCH, 256, 0, stream>>>(src, dst, ccnt, tmp, E, NCH, NBUK);
    k_build<<<NBUK, 1024, 0, stream>>>(tmp, ccnt, row_ptr, src_sorted, N, E, NBUK, NCH);

    // -------- layer 0 (scalar features, rank-1 inner BN shortcut)
    k_pool0<<<2048, 256, 0, stream>>>(vf, row_ptr, src_sorted, eps, p0, N);
    k_zero<<<1, 256, 0, stream>>>(stats, 8);
    k_p0_stats<<<1024, 256, 0, stream>>>(p0, stats, N);
    k_l0_prep<<<1, 128, 0, stream>>>(stats, W1_0, g1_0, bb1_0, A0, Sh0, N);
    k_zero<<<1, 256, 0, stream>>>(gsum, 2 * HD);
    k_gemm<2><<<2048, 256, 0, stream>>>(p0, W2_0, b2_0, A0, Sh0, stats, H, gsum, gsq, N);
    k_finalize<<<1, 128, 0, stream>>>(gsum, gsq, bn0g, bn0b, sc2, sh2, N);

    // -------- layers 1..3
    for (int l = 0; l < 3; l++) {
        k_prep_ip<<<4096, 256, 0, stream>>>(H, sc2, sh2, N * (HD / 8));
        k_zero<<<1, 256, 0, stream>>>(gsum, 2 * HD);
        k_pgemm<<<2048, 512, 0, stream>>>(H, row_ptr, src_sorted, eps, l + 1,
                                          W1s + (size_t)l * HD * HD, b1s + l * HD,
                                          Z, gsum, gsq, N);
        k_finalize<<<1, 128, 0, stream>>>(gsum, gsq, g1s + l * HD, bb1s + l * HD, sc1, sh1, N);
        k_zero<<<1, 256, 0, stream>>>(gsum, 2 * HD);
        k_gemm<1><<<2048, 256, 0, stream>>>(Z, W2s + (size_t)l * HD * HD, b2s + l * HD,
                                            sc1, sh1, nullptr, H, gsum, gsq, N);
        k_finalize<<<1, 128, 0, stream>>>(gsum, gsq, bngs + l * HD, bnbs + l * HD, sc2, sh2, N);
    }

    // -------- classifier head + softmax
    k_head<<<4096, 256, 0, stream>>>((const unsigned short*)H, sc2, sh2, fw, fb, out, N);
}